// Round 13
// baseline (248.930 us; speedup 1.0000x reference)
//
#include <hip/hip_runtime.h>
#include <stdint.h>

#define DI __device__ __forceinline__

typedef __attribute__((ext_vector_type(8))) short bfx8;
typedef __attribute__((ext_vector_type(4))) short bfx4;
typedef __attribute__((ext_vector_type(4))) float f4;

DI unsigned short f2bf(float x){
  unsigned u = __float_as_uint(x);
  u = (u + 0x7FFFu + ((u >> 16) & 1u)) >> 16;
  return (unsigned short)u;
}
DI float bf2f(unsigned short h){ return __uint_as_float(((unsigned)h) << 16); }

DI f4 mfma32(bfx8 a, bfx8 b, f4 c){
  return __builtin_amdgcn_mfma_f32_16x16x32_bf16(a, b, c, 0, 0, 0);
}
#if __has_builtin(__builtin_amdgcn_mfma_f32_16x16x16bf16_1k)
DI f4 mfma16(bfx4 a, bfx4 b, f4 c){
  return __builtin_amdgcn_mfma_f32_16x16x16bf16_1k(a, b, c, 0, 0, 0);
}
#else
DI f4 mfma16(bfx4 a, bfx4 b, f4 c){
  f4 d = c;
  asm volatile("v_mfma_f32_16x16x16_bf16 %0, %1, %2, %0" : "+v"(d) : "v"(a), "v"(b));
  return d;
}
#endif

// async global->LDS, 16B per lane; LDS dest = wave-uniform base + lane*16
DI void gload16(const void* g, void* l){
  __builtin_amdgcn_global_load_lds(
      (__attribute__((address_space(1))) void*)g,
      (__attribute__((address_space(3))) void*)l, 16, 0, 0);
}

// Fragment layouts (all 16-bit elems):
//   Qf/Kf[bh][tile][lane][16]: elem[kf*8+j] = M[tile*16 + (lane&15)][kf*32 + 8*(lane>>4) + j]
//   Vf  [bh][tile][lane][16]: elem[df*4+j] = V[tile*16 + 4*(lane>>4) + j][df*16 + (lane&15)]
//   ivf [b][tt][st][lane][4]: elem[r] = 1/S at (s = st*16 + (lane&15), t = tt*16 + 4*(lane>>4) + r)

// ---------------- cast f32 -> bf16 (4-wide) ----------------
__global__ void k_cast(const float* __restrict__ src, unsigned short* __restrict__ dst, int n4){
  int i = blockIdx.x*256 + threadIdx.x;
  if (i < n4){
    const float4 v = ((const float4*)src)[i];
    bfx4 o;
    o[0] = (short)f2bf(v.x); o[1] = (short)f2bf(v.y);
    o[2] = (short)f2bf(v.z); o[3] = (short)f2bf(v.w);
    *(bfx4*)(dst + (size_t)i*4) = o;
  }
}

// merged weight cast: 4 matrices (1024x1024 f32) -> contiguous bf16 dsts
__global__ void k_castw(const float* __restrict__ s0, const float* __restrict__ s1,
                        const float* __restrict__ s2, const float* __restrict__ s3,
                        unsigned short* __restrict__ dst){
  int i = blockIdx.x*256 + threadIdx.x;      // < 262144
  const float* src = (blockIdx.y==0) ? s0 : (blockIdx.y==1) ? s1 : (blockIdx.y==2) ? s2 : s3;
  const float4 v = ((const float4*)src)[i];
  bfx4 o;
  o[0] = (short)f2bf(v.x); o[1] = (short)f2bf(v.y);
  o[2] = (short)f2bf(v.z); o[3] = (short)f2bf(v.w);
  *(bfx4*)(dst + (size_t)blockIdx.y*1048576 + (size_t)i*4) = o;
}

// relk_bf: [272][64] zero-padded rows; relvT_bf: [64][288] = rel_v^T zero-padded cols
__global__ void k_relprep(const float* __restrict__ rlk, const float* __restrict__ rlv,
                          unsigned short* __restrict__ relk_bf, unsigned short* __restrict__ relvT_bf){
  int i = blockIdx.x*256 + threadIdx.x;
  if (i < 272*64){
    int r = i >> 6, d = i & 63;
    relk_bf[i] = (r < 257) ? f2bf(rlk[r*64 + d]) : (unsigned short)0;
  }
  if (i < 64*288){
    int d = i / 288, r = i % 288;
    relvT_bf[i] = (r < 257) ? f2bf(rlv[(size_t)r*64 + d]) : (unsigned short)0;
  }
}

// ---------------- QKV projections: counted-vmcnt double-buffered pipeline ----------------
__global__ __launch_bounds__(256, 3) void k_qkv(
    const unsigned short* __restrict__ xbf, const unsigned short* __restrict__ wqkv,
    unsigned short* __restrict__ Qf, unsigned short* __restrict__ Kf,
    unsigned short* __restrict__ Vf)
{
  __shared__ __align__(16) unsigned short smem[2][8192];   // 2 x 16 KB: A blocks 0-7, B blocks 8-15
  const int nt = blockIdx.x;
  const int b  = blockIdx.y;
  const int st = blockIdx.z;
  const int w = threadIdx.x >> 6, lane = threadIdx.x & 63;
  const int wr = w >> 1, wc = w & 1;
  const int p = lane & 15, g = lane >> 4;
  const int s0 = st*128;
  const int n0 = nt*128;
  const f4 fz = {0.f,0.f,0.f,0.f};
  f4 acc[4][4];
#pragma unroll
  for (int m=0;m<4;++m)
#pragma unroll
    for (int n=0;n<4;++n) acc[m][n] = fz;

  const int j0 = w*2, j1 = w*2 + 1;
  const unsigned short* gA = xbf  + (size_t)((s0 + p)*4 + b)*1024 + g*8;
  const unsigned short* gB = wqkv + (size_t)(n0 + p)*1024 + g*8;

  {
    unsigned short* d0 = &smem[0][0];
    gload16(gA + (size_t)j0*65536, d0 + j0*512);
    gload16(gA + (size_t)j1*65536, d0 + j1*512);
    gload16(gB + (size_t)j0*16384, d0 + 4096 + j0*512);
    gload16(gB + (size_t)j1*16384, d0 + 4096 + j1*512);
  }

  for (int it=0; it<32; ++it){
    const int cur = it & 1;
    if (it < 31){
      const int kn = (it+1)*32;
      unsigned short* dn = &smem[cur^1][0];
      gload16(gA + (size_t)j0*65536 + kn, dn + j0*512);
      gload16(gA + (size_t)j1*65536 + kn, dn + j1*512);
      gload16(gB + (size_t)j0*16384 + kn, dn + 4096 + j0*512);
      gload16(gB + (size_t)j1*16384 + kn, dn + 4096 + j1*512);
      asm volatile("s_waitcnt vmcnt(4)" ::: "memory");
    } else {
      asm volatile("s_waitcnt vmcnt(0)" ::: "memory");
    }
    __builtin_amdgcn_sched_barrier(0);
    __builtin_amdgcn_s_barrier();
    __builtin_amdgcn_sched_barrier(0);
    {
      const unsigned short* Ab = &smem[cur][0];
      bfx8 af[4], bfr[4];
#pragma unroll
      for (int m=0;m<4;++m) af[m] = *(const bfx8*)(Ab + (wr*4+m)*512 + lane*8);
#pragma unroll
      for (int n=0;n<4;++n) bfr[n] = *(const bfx8*)(Ab + 4096 + (wc*4+n)*512 + lane*8);
#pragma unroll
      for (int m=0;m<4;++m)
#pragma unroll
        for (int n=0;n<4;++n)
          acc[m][n] = mfma32(af[m], bfr[n], acc[m][n]);
    }
    __builtin_amdgcn_sched_barrier(0);
    __builtin_amdgcn_s_barrier();
    __builtin_amdgcn_sched_barrier(0);
  }

  const int n64 = n0 + wc*64;
  const int sec = n64 >> 10;            // 0 Q, 1 K, 2 V
  const int h = (n64 & 1023) >> 6;
  float* es = (float*)&smem[0][0] + w*1280;

  if (sec < 2){
    const float scl = (sec == 0) ? 0.125f : 1.0f;
    unsigned short* dst = (sec == 0) ? Qf : Kf;
#pragma unroll
    for (int m=0;m<4;++m){
#pragma unroll
      for (int n=0;n<4;++n)
#pragma unroll
        for (int r=0;r<4;++r)
          es[(4*g + r)*80 + 16*n + p] = acc[m][n][r] * scl;
      __syncthreads();
      f4 v0 = *(const f4*)&es[p*80 + 8*g];
      f4 v1 = *(const f4*)&es[p*80 + 8*g + 4];
      f4 v2 = *(const f4*)&es[p*80 + 32 + 8*g];
      f4 v3 = *(const f4*)&es[p*80 + 32 + 8*g + 4];
      bfx8 lo, hi;
#pragma unroll
      for (int j=0;j<4;++j){
        lo[j]   = (short)f2bf(v0[j]);
        lo[j+4] = (short)f2bf(v1[j]);
        hi[j]   = (short)f2bf(v2[j]);
        hi[j+4] = (short)f2bf(v3[j]);
      }
      size_t fb = ((size_t)(b*16 + h)*64 + (st*8 + wr*4 + m))*1024 + (size_t)lane*16;
      *(bfx8*)(dst + fb) = lo;
      *(bfx8*)(dst + fb + 8) = hi;
      __syncthreads();
    }
  } else {
#pragma unroll
    for (int m=0;m<4;++m){
#pragma unroll
      for (int n=0;n<4;++n)
        *(f4*)&es[(16*n + p)*20 + 4*g] = acc[m][n];
      __syncthreads();
      f4 vv0 = *(const f4*)&es[(p)*20 + 4*g];
      f4 vv1 = *(const f4*)&es[(16 + p)*20 + 4*g];
      f4 vv2 = *(const f4*)&es[(32 + p)*20 + 4*g];
      f4 vv3 = *(const f4*)&es[(48 + p)*20 + 4*g];
      bfx8 lo, hi;
#pragma unroll
      for (int j=0;j<4;++j){
        lo[j]   = (short)f2bf(vv0[j]);
        lo[j+4] = (short)f2bf(vv1[j]);
        hi[j]   = (short)f2bf(vv2[j]);
        hi[j+4] = (short)f2bf(vv3[j]);
      }
      size_t fb = ((size_t)(b*16 + h)*64 + (st*8 + wr*4 + m))*1024 + (size_t)lane*16;
      *(bfx8*)(Vf + fb) = lo;
      *(bfx8*)(Vf + fb + 8) = hi;
      __syncthreads();
    }
  }
}

// ---------------- Qr2 producer, write-coalesced: all 16 heads per block ----------------
__global__ __launch_bounds__(256) void k_qr(
    const unsigned short* __restrict__ Qf, const unsigned short* __restrict__ relk,
    unsigned short* __restrict__ Qr2)
{
  __shared__ __align__(16) unsigned short sst[16][16][24];
  const int bx = blockIdx.x;
  const int b  = bx & 3;
  const int st = (bx >> 2) & 63;
  const int uh = bx >> 8;
  const int w = threadIdx.x >> 6, lane = threadIdx.x & 63;
  const int p = lane & 15, g = lane >> 4;
  const int s0 = st << 4;
  const f4 fz = {0.f,0.f,0.f,0.f};

  bfx8 a0[4], a1[4];
#pragma unroll
  for (int hh=0; hh<4; ++hh){
    size_t fb = (((size_t)(b*16 + w*4 + hh))*64 + st)*1024 + (size_t)lane*16;
    a0[hh] = *(const bfx8*)(Qf + fb);
    a1[hh] = *(const bfx8*)(Qf + fb + 8);
  }

  const int c0 = uh ? 9 : 0;
  const int c1 = uh ? 17 : 9;
  const int so = threadIdx.x >> 4, uo = threadIdx.x & 15;

  for (int c=c0; c<c1; ++c){
    const int r0 = c << 4;
    bfx8 b0 = *(const bfx8*)(relk + (size_t)(r0 + p)*64 + 8*g);
    bfx8 b1 = *(const bfx8*)(relk + (size_t)(r0 + p)*64 + 32 + 8*g);
#pragma unroll
    for (int hh=0; hh<4; ++hh){
      f4 acc = mfma32(a1[hh], b1, mfma32(a0[hh], b0, fz));
#pragma unroll
      for (int r=0; r<4; ++r)
        sst[4*g + r][p][w*4 + hh] = f2bf(acc[r]);
    }
    __syncthreads();
    bfx8 v0 = *(const bfx8*)&sst[so][uo][0];
    bfx8 v1 = *(const bfx8*)&sst[so][uo][8];
    size_t ga = (((size_t)b*1024 + s0 + so)*272 + r0 + uo)*16;
    *(bfx8*)(Qr2 + ga) = v0;
    *(bfx8*)(Qr2 + ga + 8) = v1;
    __syncthreads();
  }
}

// ---------------- softmax denominator -> ivf; register-pipelined head loop (PF=4) ----------------
// ONE WAVE per (b, s-tile, t-tile), all 16 heads in-lane. VGPR-starved serial chain in the old
// version (VGPR=40) -> explicit prefetch-depth-4 pipeline, all indices compile-time.
__global__ __launch_bounds__(256, 2) void k_s(
    const unsigned short* __restrict__ Qf, const unsigned short* __restrict__ Kf,
    const unsigned short* __restrict__ Qr2, float* __restrict__ ivf)
{
  const int pbid = blockIdx.x;            // (st<<6)|(ttg<<2)|b
  const int b   = pbid & 3;
  const int ttg = (pbid >> 2) & 15;
  const int st  = pbid >> 6;
  const int w = threadIdx.x >> 6, lane = threadIdx.x & 63;
  const int tt = ttg*4 + w;
  const int p = lane & 15, g = lane >> 4;
  const int s0 = st << 4, t0 = tt << 4;
  const int s = s0 + p;
  const f4 fz = {0.f,0.f,0.f,0.f};

  bfx8 rv[4][2];
#pragma unroll
  for (int r=0; r<4; ++r){
    int t = t0 + 4*g + r;
    int u = s - t + 128; u = u < 0 ? 0 : (u > 256 ? 256 : u);
    const unsigned short* q = Qr2 + (((size_t)b*1024 + s)*272 + u)*16;
    rv[r][0] = *(const bfx8*)q;
    rv[r][1] = *(const bfx8*)(q + 8);
  }

  const unsigned short* qbp = Qf + ((size_t)(b*16)*64 + st)*1024 + (size_t)lane*16;
  const unsigned short* kbp = Kf + ((size_t)(b*16)*64 + tt)*1024 + (size_t)lane*16;

  bfx8 qq[16][2], kk[16][2];
#define LOADH(H) { \
    qq[H][0] = *(const bfx8*)(qbp + (size_t)(H)*65536); \
    qq[H][1] = *(const bfx8*)(qbp + (size_t)(H)*65536 + 8); \
    kk[H][0] = *(const bfx8*)(kbp + (size_t)(H)*65536); \
    kk[H][1] = *(const bfx8*)(kbp + (size_t)(H)*65536 + 8); }

  LOADH(0) LOADH(1) LOADH(2) LOADH(3)

  f4 ps = fz;
#pragma unroll
  for (int h=0; h<16; ++h){
    if (h + 4 < 16){
      const int hn = h + 4;
      qq[hn][0] = *(const bfx8*)(qbp + (size_t)hn*65536);
      qq[hn][1] = *(const bfx8*)(qbp + (size_t)hn*65536 + 8);
      kk[hn][0] = *(const bfx8*)(kbp + (size_t)hn*65536);
      kk[hn][1] = *(const bfx8*)(kbp + (size_t)hn*65536 + 8);
    }
    f4 sc = mfma32(kk[h][1], qq[h][1], mfma32(kk[h][0], qq[h][0], fz));
    const int hg = h >> 3, hr = h & 7;
#pragma unroll
    for (int r=0; r<4; ++r)
      ps[r] += __expf(sc[r] + bf2f((unsigned short)rv[r][hg][hr]));
  }
#undef LOADH

  f4 inv;
#pragma unroll
  for (int r=0; r<4; ++r) inv[r] = 1.0f / ps[r];
  *(f4*)(ivf + (((size_t)(b*64 + tt)*64 + st)*64 + lane)*4) = inv;
}

// ---------------- far attention: barrier-free, fragment loads, balanced strided far list ----------------
__global__ __launch_bounds__(256, 3) void k_far(
    const unsigned short* __restrict__ Qf, const unsigned short* __restrict__ Kf,
    const unsigned short* __restrict__ Vf, const unsigned short* __restrict__ Qr2,
    const float* __restrict__ ivf, float* __restrict__ tails,
    unsigned short* __restrict__ op)
{
  __shared__ __align__(16) float slab[4][16][68];
  const int pbid  = blockIdx.x;
  const int b     = pbid & 3;
  const int part  = (pbid >> 2) & 3;
  const int hhalf = (pbid >> 4) & 1;
  const int st    = pbid >> 5;
  const int s0 = st << 4;
  const int w = threadIdx.x >> 6, lane = threadIdx.x & 63;
  const int p = lane & 15, g = lane >> 4;
  const int s = s0 + p;
  const int h0 = hhalf*8 + w*2;
  const f4 fz = {0.f,0.f,0.f,0.f};

  bfx8 qf[2][2]; float qr0[2], qr1[2];
#pragma unroll
  for (int hh=0; hh<2; ++hh){
    size_t bh = (size_t)(b*16 + h0 + hh);
    size_t qb = (bh*64 + st)*1024 + (size_t)lane*16;
    qf[hh][0] = *(const bfx8*)(Qf + qb);
    qf[hh][1] = *(const bfx8*)(Qf + qb + 8);
    qr0[hh] = bf2f(Qr2[(((size_t)b*1024 + s)*272 + 0)*16 + (h0+hh)]);
    qr1[hh] = bf2f(Qr2[(((size_t)b*1024 + s)*272 + 256)*16 + (h0+hh)]);
  }

  f4 o[2][4];
#pragma unroll
  for (int hh=0; hh<2; ++hh)
#pragma unroll
    for (int df=0; df<4; ++df) o[hh][df] = fz;
  float tl0[2] = {0.f,0.f};
  float tl1[2] = {0.f,0.f};

  const int tlo = (st-8 < 0) ? 0 : st-8;
  const int thi = (st+8 > 63) ? 63 : st+8;
  const int nband = thi - tlo + 1;
  const int nfar = 64 - nband;

  bfx8 kc[2][2]; bfx4 vc[2][4]; f4 is;
  bfx8 kn[2][2]; bfx4 vn[2][4]; f4 isn;

  int idx = part;
  {
    const int ti = (idx < tlo) ? idx : idx + nband;
#pragma unroll
    for (int hh=0; hh<2; ++hh){
      size_t fb = (((size_t)(b*16 + h0 + hh))*64 + ti)*1024 + (size_t)lane*16;
      kc[hh][0] = *(const bfx8*)(Kf + fb);
      kc[hh][1] = *(const bfx8*)(Kf + fb + 8);
#pragma unroll
      for (int df=0; df<4; ++df)
        vc[hh][df] = *(const bfx4*)(Vf + fb + df*4);
    }
    is = *(const f4*)(ivf + (((size_t)(b*64 + ti)*64 + st)*64 + lane)*4);
  }

  while (idx < nfar){
    const int idn = idx + 4;
    if (idn < nfar){
      const int tn = (idn < tlo) ? idn : idn + nband;
#pragma unroll
      for (int hh=0; hh<2; ++hh){
        size_t fb = (((size_t)(b*16 + h0 + hh))*64 + tn)*1024 + (size_t)lane*16;
        kn[hh][0] = *(const bfx8*)(Kf + fb);
        kn[hh][1] = *(const bfx8*)(Kf + fb + 8);
#pragma unroll
        for (int df=0; df<4; ++df)
          vn[hh][df] = *(const bfx4*)(Vf + fb + df*4);
      }
      isn = *(const f4*)(ivf + (((size_t)(b*64 + tn)*64 + st)*64 + lane)*4);
    }

    const int ti = (idx < tlo) ? idx : idx + nband;
    const bool hiSide = (ti < st);
#pragma unroll
    for (int hh=0; hh<2; ++hh){
      f4 sc = mfma32(kc[hh][1], qf[hh][1], mfma32(kc[hh][0], qf[hh][0], fz));
      const float qa = hiSide ? qr1[hh] : qr0[hh];
      f4 at;
#pragma unroll
      for (int r=0; r<4; ++r) at[r] = __expf(sc[r] + qa) * is[r];
      float tsum = at[0] + at[1] + at[2] + at[3];
      if (hiSide) tl1[hh] += tsum; else tl0[hh] += tsum;
      bfx4 pk;
#pragma unroll
      for (int r=0; r<4; ++r) pk[r] = (short)f2bf(at[r]);
#pragma unroll
      for (int df=0; df<4; ++df)
        o[hh][df] = mfma16(vc[hh][df], pk, o[hh][df]);
    }

    if (idn < nfar){
#pragma unroll
      for (int hh=0; hh<2; ++hh){
        kc[hh][0] = kn[hh][0]; kc[hh][1] = kn[hh][1];
#pragma unroll
        for (int df=0; df<4; ++df) vc[hh][df] = vn[hh][df];
      }
      is = isn;
    }
    idx = idn;
  }

  // tail buckets for this part
#pragma unroll
  for (int hh=0; hh<2; ++hh){
    float v0 = tl0[hh];
    v0 += __shfl_xor(v0, 16, 64);
    v0 += __shfl_xor(v0, 32, 64);
    float v1 = tl1[hh];
    v1 += __shfl_xor(v1, 16, 64);
    v1 += __shfl_xor(v1, 32, 64);
    if (g == 0){
      size_t tix = ((size_t)(part*64 + b*16 + h0 + hh)*1024 + s)*2;
      tails[tix + 0] = v0;
      tails[tix + 1] = v1;
    }
  }

  // transpose epilogue -> bf16 partial output for this part
  unsigned short* dst = op + (size_t)part * 4194304;
#pragma unroll
  for (int hh=0; hh<2; ++hh){
    float (*tb)[68] = slab[w];
#pragma unroll
    for (int df=0; df<4; ++df)
      *(f4*)&tb[p][df*16 + 4*g] = o[hh][df];
    __syncthreads();
    const int srow = lane >> 2, quad = lane & 3;
    f4 r0 = *(const f4*)&tb[srow][quad*16 + 0];
    f4 r1 = *(const f4*)&tb[srow][quad*16 + 4];
    f4 r2 = *(const f4*)&tb[srow][quad*16 + 8];
    f4 r3 = *(const f4*)&tb[srow][quad*16 + 12];
    bfx8 pa, pb;
#pragma unroll
    for (int j=0; j<4; ++j){
      pa[j]   = (short)f2bf(r0[j]);
      pa[j+4] = (short)f2bf(r1[j]);
      pb[j]   = (short)f2bf(r2[j]);
      pb[j+4] = (short)f2bf(r3[j]);
    }
    size_t addr = ((size_t)b*1024 + s0 + srow)*1024 + (h0+hh)*64 + quad*16;
    *(bfx8*)(dst + addr) = pa;
    *(bfx8*)(dst + addr + 8) = pb;
    __syncthreads();
  }
}

// ---------------- near attention, head-split: (b, st, hhalf); 4 waves x 2 heads ----------------
__global__ __launch_bounds__(256, 2) void k_near(
    const unsigned short* __restrict__ Qf, const unsigned short* __restrict__ Kf,
    const unsigned short* __restrict__ Vf, const unsigned short* __restrict__ Qr2,
    const float* __restrict__ ivf, const unsigned short* __restrict__ relvT,
    const float* __restrict__ relv, const float* __restrict__ tails,
    const unsigned short* __restrict__ op, unsigned short* __restrict__ out1)
{
  __shared__ __align__(16) unsigned short skew[128*264];   // 67,584 B
  const int pbid = blockIdx.x;
  const int xcd = pbid & 7;
  const int b = xcd >> 1;
  const int hhalf = (pbid >> 3) & 1;
  const int st = ((pbid >> 4) << 1) | (xcd & 1);
  const int s0 = st << 4;
  const int w = threadIdx.x >> 6;
  const int lane = threadIdx.x & 63;
  const int p = lane & 15, g = lane >> 4;
  const int s = s0 + p;
  const int hl0 = w * 2;                 // local head base (skew rows)
  const int h0 = hhalf*8 + hl0;          // global head base (memory)
  const f4 fz = {0.f,0.f,0.f,0.f};

  {
    unsigned* zp = (unsigned*)skew + w*4224;
    for (int i = lane; i < 4224; i += 64) zp[i] = 0u;
  }

  bfx8 qf[2][2];
#pragma unroll
  for (int hh=0; hh<2; ++hh){
    size_t qb = (((size_t)(b*16 + h0 + hh))*64 + st)*1024 + (size_t)lane*16;
    qf[hh][0] = *(const bfx8*)(Qf + qb);
    qf[hh][1] = *(const bfx8*)(Qf + qb + 8);
  }

  f4 o[2][4];
#pragma unroll
  for (int hh=0; hh<2; ++hh)
#pragma unroll
    for (int df=0; df<4; ++df) o[hh][df] = fz;

  float tl0[2] = {0.f,0.f};
  float tl1[2] = {0.f,0.f};

  const int tlo = (st-8 < 0) ? 0 : st-8;
  const int thi = (st+8 > 63) ? 63 : st+8;

  bfx8 kc[2][2]; bfx4 vc[2][4]; unsigned short qc[2][4]; f4 is;
  bfx8 kn[2][2]; bfx4 vn[2][4]; unsigned short qn[2][4]; f4 isn;

#pragma unroll
  for (int hh=0; hh<2; ++hh){
    size_t bh = (size_t)(b*16 + h0 + hh);
    size_t fb = (bh*64 + tlo)*1024 + (size_t)lane*16;
    kc[hh][0] = *(const bfx8*)(Kf + fb);
    kc[hh][1] = *(const bfx8*)(Kf + fb + 8);
#pragma unroll
    for (int df=0; df<4; ++df)
      vc[hh][df] = *(const bfx4*)(Vf + fb + df*4);
#pragma unroll
    for (int r=0; r<4; ++r){
      int t = (tlo<<4) + 4*g + r;
      int u = s - t + 128; u = u < 0 ? 0 : (u > 256 ? 256 : u);
      qc[hh][r] = Qr2[(((size_t)b*1024 + s)*272 + u)*16 + (h0+hh)];
    }
  }
  is = *(const f4*)(ivf + (((size_t)(b*64 + tlo)*64 + st)*64 + lane)*4);

  for (int ti = tlo; ti <= thi; ++ti){
    const int t0 = ti << 4;

    if (ti < thi){
      const int tn = ti + 1;
#pragma unroll
      for (int hh=0; hh<2; ++hh){
        size_t bh = (size_t)(b*16 + h0 + hh);
        size_t fb = (bh*64 + tn)*1024 + (size_t)lane*16;
        kn[hh][0] = *(const bfx8*)(Kf + fb);
        kn[hh][1] = *(const bfx8*)(Kf + fb + 8);
#pragma unroll
        for (int df=0; df<4; ++df)
          vn[hh][df] = *(const bfx4*)(Vf + fb + df*4);
#pragma unroll
        for (int r=0; r<4; ++r){
          int t = (tn<<4) + 4*g + r;
          int u = s - t + 128; u = u < 0 ? 0 : (u > 256 ? 256 : u);
          qn[hh][r] = Qr2[(((size_t)b*1024 + s)*272 + u)*16 + (h0+hh)];
        }
      }
      isn = *(const f4*)(ivf + (((size_t)(b*64 + tn)*64 + st)*64 + lane)*4);
    }

#pragma unroll
    for (int hh=0; hh<2; ++hh){
      f4 sc = mfma32(kc[hh][1], qf[hh][1], mfma32(kc[hh][0], qf[hh][0], fz));
      f4 at;
#pragma unroll
      for (int r=0; r<4; ++r) at[r] = __expf(sc[r] + bf2f(qc[hh][r])) * is[r];
      const int row = (hl0 + hh)*16 + p;
#pragma unroll
      for (int r=0; r<4; ++r){
        int t = t0 + 4*g + r;
        int u = s - t + 128;
        float a = at[r];
        if (u <= 0) tl0[hh] += a;
        else if (u >= 256) tl1[hh] += a;
        else skew[row*264 + u] = f2bf(a);
      }
      bfx4 pk;
#pragma unroll
      for (int r=0; r<4; ++r) pk[r] = (short)f2bf(at[r]);
#pragma unroll
      for (int df=0; df<4; ++df)
        o[hh][df] = mfma16(vc[hh][df], pk, o[hh][df]);
    }

    if (ti < thi){
#pragma unroll
      for (int hh=0; hh<2; ++hh){
#pragma unroll
        for (int kf=0; kf<2; ++kf) kc[hh][kf] = kn[hh][kf];
#pragma unroll
        for (int df=0; df<4; ++df) vc[hh][df] = vn[hh][df];
#pragma unroll
        for (int r=0; r<4; ++r) qc[hh][r] = qn[hh][r];
      }
      is = isn;
    }
  }

  __syncthreads();

  // ---- fused out2 = rel_v^T @ skew (own-wave rows only; local head rows) ----
  f4 acc2[2][4];
#pragma unroll
  for (int hh=0; hh<2; ++hh)
#pragma unroll
    for (int df=0; df<4; ++df) acc2[hh][df] = fz;
#pragma unroll
  for (int k0=0; k0<256; k0+=32){
    bfx8 bb0 = *(const bfx8*)&skew[(hl0*16 + p)*264 + k0 + 8*g];
    bfx8 bb1 = *(const bfx8*)&skew[((hl0+1)*16 + p)*264 + k0 + 8*g];
#pragma unroll
    for (int df=0; df<4; ++df){
      bfx8 a = *(const bfx8*)(relvT + (size_t)(df*16 + p)*288 + k0 + 8*g);
      acc2[0][df] = mfma32(a, bb0, acc2[0][df]);
      acc2[1][df] = mfma32(a, bb1, acc2[1][df]);
    }
  }

  f4 rv0[4], rv1[4];
#pragma unroll
  for (int df=0; df<4; ++df){
    rv0[df] = *(const f4*)(relv + df*16 + 4*g);
    rv1[df] = *(const f4*)(relv + 16384 + df*16 + 4*g);
  }
#pragma unroll
  for (int hh=0; hh<2; ++hh){
    float tv0 = tl0[hh];
    tv0 += __shfl_xor(tv0, 16, 64);
    tv0 += __shfl_xor(tv0, 32, 64);
    float tv1 = tl1[hh];
    tv1 += __shfl_xor(tv1, 16, 64);
    tv1 += __shfl_xor(tv1, 32, 64);
    size_t bh = (size_t)(b*16 + h0 + hh);
#pragma unroll
    for (int part=0; part<4; ++part){
      size_t tix = ((size_t)(part*64) + bh)*2048 + (size_t)s*2;
      tv0 += tails[tix + 0];
      tv1 += tails[tix + 1];
    }
#pragma unroll
    for (int df=0; df<4; ++df)
#pragma unroll
      for (int r=0; r<4; ++r)
        o[hh][df][r] += acc2[hh][df][r] + tv0*rv0[df][r] + tv1*rv1[df][r];
  }

  __syncthreads();

  float* slabBase = (float*)skew;
  float (*tb)[68] = (float(*)[68])(slabBase + w*(16*68));
#pragma unroll
  for (int hh=0; hh<2; ++hh){
#pragma unroll
    for (int df=0; df<4; ++df)
      *(f4*)&tb[p][df*16 + 4*g] = o[hh][df];
    __syncthreads();
    const int srow = lane >> 2, quad = lane & 3;
    f4 r0 = *(const f4*)&tb[srow][quad*16 + 0];
    f4 r1 = *(const f4*)&tb[srow][quad*16 + 4];
    f4 r2 = *(const f4*)&tb[srow][quad*16 + 8];
    f4 r3 = *(const f4*)&tb[srow][quad*16 + 12];
    size_t addr = ((size_t)b*1024 + s0 + srow)*1024 + (h0+hh)*64 + quad*16;
    bfx8 pa, pb;
#pragma unroll
    for (int j=0; j<4; ++j){
      float a0 = r0[j], a1 = r1[j], a2 = r2[j], a3 = r3[j];
#pragma unroll
      for (int part=0; part<4; ++part){
        const unsigned short* pp = op + (size_t)part*4194304 + addr;
        bfx8 q0 = *(const bfx8*)pp;
        bfx8 q1 = *(const bfx8*)(pp + 8);
        a0 += bf2f((unsigned short)q0[j]);
        a1 += bf2f((unsigned short)q0[j+4]);
        a2 += bf2f((unsigned short)q1[j]);
        a3 += bf2f((unsigned short)q1[j+4]);
      }
      pa[j]   = (short)f2bf(a0);
      pa[j+4] = (short)f2bf(a1);
      pb[j]   = (short)f2bf(a2);
      pb[j+4] = (short)f2bf(a3);
    }
    *(bfx8*)(out1 + addr) = pa;
    *(bfx8*)(out1 + addr + 8) = pb;
    __syncthreads();
  }
}

// ---------------- final projection: counted-vmcnt double-buffered pipeline ----------------
__global__ __launch_bounds__(256) void k_wo(
    const unsigned short* __restrict__ out1, const unsigned short* __restrict__ wo,
    const float* __restrict__ bo, float* __restrict__ dout)
{
  __shared__ __align__(16) unsigned short smem[2][6144];
  const int nt = blockIdx.x;
  const int mt = blockIdx.y;
  const int w = threadIdx.x >> 6, lane = threadIdx.x & 63;
  const int wr = w >> 1, wc = w & 1;
  const int p = lane & 15, g = lane >> 4;
  const int m0 = mt*64, n0 = nt*128;
  const f4 fz = {0.f,0.f,0.f,0.f};
  f4 acc[2][4];
#pragma unroll
  for (int m=0;m<2;++m)
#pragma unroll
    for (int n=0;n<4;++n) acc[m][n] = fz;

  const int j0 = w*2, j1 = w*2 + 1;
  const unsigned short* gA = out1 + (size_t)(m0 + p)*1024 + g*8;
  const unsigned short* gB = wo   + (size_t)(n0 + p)*1024 + g*8;

  {
    unsigned short* d0 = &smem[0][0];
    gload16(gA + (size_t)w*16384, d0 + w*512);
    gload16(gB + (size_t)j0*16384, d0 + 2048 + j0*512);
    gload16(gB + (size_t)j1*16384, d0 + 2048 + j1*512);
  }

  for (int it=0; it<32; ++it){
    const int cur = it & 1;
    if (it < 31){
      const int kn = (it+1)*32;
      unsigned short* dn = &smem[cur^1][0];
      gload16(gA + (size_t)w*16384 + kn, dn + w*512);
      gload16(gB + (size_t)j0*16384 + kn, dn + 2048 + j0*512);
      gload16(gB + (size_t)j1*16384 + kn, dn + 2048 + j1*512);
      asm volatile("s_waitcnt vmcnt(3)" ::: "memory");
    } else {
      asm volatile("s_waitcnt vmcnt(0)" ::: "memory");
    }
    __builtin_amdgcn_sched_barrier(0);
    __builtin_amdgcn_s_barrier();
    __builtin_amdgcn_sched_barrier(0);
    {
      const unsigned short* Ab = &smem[cur][0];
      bfx8 af[2], bfr[4];
#pragma unroll
      for (int m=0;m<2;++m) af[m] = *(const bfx8*)(Ab + (wr*2+m)*512 + lane*8);
#pragma unroll
      for (int n=0;n<4;++n) bfr[n] = *(const bfx8*)(Ab + 2048 + (wc*4+n)*512 + lane*8);
#pragma unroll
      for (int m=0;m<2;++m)
#pragma unroll
        for (int n=0;n<4;++n)
          acc[m][n] = mfma32(af[m], bfr[n], acc[m][n]);
    }
    __builtin_amdgcn_sched_barrier(0);
    __builtin_amdgcn_s_barrier();
    __builtin_amdgcn_sched_barrier(0);
  }

#pragma unroll
  for (int n=0;n<4;++n){
    const int col = n0 + wc*64 + n*16 + p;
    const float bias = bo[col];
#pragma unroll
    for (int m=0;m<2;++m)
#pragma unroll
      for (int r=0;r<4;++r){
        int row = m0 + wr*32 + m*16 + 4*g + r;
        int bb = row >> 10, s = row & 1023;
        dout[((size_t)s*4 + bb)*1024 + col] = acc[m][n][r] + bias;
      }
  }
}

extern "C" void kernel_launch(void* const* d_in, const int* in_sizes, int n_in,
                              void* d_out, int out_size, void* d_ws, size_t ws_size,
                              hipStream_t stream){
  const float* x   = (const float*)d_in[0];
  const float* wq  = (const float*)d_in[1];
  const float* wk  = (const float*)d_in[2];
  const float* wv  = (const float*)d_in[3];
  const float* wo  = (const float*)d_in[4];
  const float* bo  = (const float*)d_in[5];
  const float* rlk = (const float*)d_in[6];
  const float* rlv = (const float*)d_in[7];
  char* ws = (char*)d_ws;

  unsigned short* x_bf    = (unsigned short*)(ws + 0);
  unsigned short* wq_bf   = (unsigned short*)(ws + 8388608);   // [wq|wk|wv|wo] contiguous
  unsigned short* relk_bf = (unsigned short*)(ws + 16777216);
  unsigned short* relvT_bf= (unsigned short*)(ws + 16812032);
  unsigned short* Qf      = (unsigned short*)(ws + 16848896);   // fragment layout
  unsigned short* Kf      = (unsigned short*)(ws + 25237504);   // fragment layout
  unsigned short* Vf      = (unsigned short*)(ws + 33626112);   // fragment layout
  unsigned short* Qr2     = (unsigned short*)(ws + 42014720);   // 35.65 MB -> 77666304
  float*          tails   = (float*)        (ws + 77666304);   // 2 MB -> 79763456
  unsigned short* op      = (unsigned short*)(ws + 79763456);   // 32 MB (4 parts) -> 113317888
  unsigned short* out1    = (unsigned short*)(ws + 113317888);  // 8 MB -> 121706496
  float*          ivf     = (float*)        (ws + 121706496);  // 16 MB -> 138483712
  unsigned short* wo_bf   = (unsigned short*)(ws + 14680064);

  k_cast<<<4096, 256, 0, stream>>>(x, x_bf, 1048576);
  k_castw<<<dim3(1024,4), 256, 0, stream>>>(wq, wk, wv, wo, wq_bf);
  k_relprep<<<72, 256, 0, stream>>>(rlk, rlv, relk_bf, relvT_bf);

  k_qkv<<<dim3(24,4,8), 256, 0, stream>>>(x_bf, wq_bf, Qf, Kf, Vf);
  k_qr<<<512, 256, 0, stream>>>(Qf, relk_bf, Qr2);

  k_s  <<<4096, 256, 0, stream>>>(Qf, Kf, Qr2, ivf);
  k_far<<<2048, 256, 0, stream>>>(Qf, Kf, Vf, Qr2, ivf, tails, op);
  k_near<<<512, 256, 0, stream>>>(Qf, Kf, Vf, Qr2, ivf, relvT_bf, rlv, tails, op, out1);
  k_wo<<<dim3(8,64), 256, 0, stream>>>(out1, wo_bf, bo, (float*)d_out);
}

// Round 14
// 226.570 us; speedup vs baseline: 1.0987x; 1.0987x over previous
//
#include <hip/hip_runtime.h>
#include <stdint.h>

#define DI __device__ __forceinline__

typedef __attribute__((ext_vector_type(8))) short bfx8;
typedef __attribute__((ext_vector_type(4))) short bfx4;
typedef __attribute__((ext_vector_type(4))) float f4;

DI unsigned short f2bf(float x){
  unsigned u = __float_as_uint(x);
  u = (u + 0x7FFFu + ((u >> 16) & 1u)) >> 16;
  return (unsigned short)u;
}
DI float bf2f(unsigned short h){ return __uint_as_float(((unsigned)h) << 16); }

DI f4 mfma32(bfx8 a, bfx8 b, f4 c){
  return __builtin_amdgcn_mfma_f32_16x16x32_bf16(a, b, c, 0, 0, 0);
}
#if __has_builtin(__builtin_amdgcn_mfma_f32_16x16x16bf16_1k)
DI f4 mfma16(bfx4 a, bfx4 b, f4 c){
  return __builtin_amdgcn_mfma_f32_16x16x16bf16_1k(a, b, c, 0, 0, 0);
}
#else
DI f4 mfma16(bfx4 a, bfx4 b, f4 c){
  f4 d = c;
  asm volatile("v_mfma_f32_16x16x16_bf16 %0, %1, %2, %0" : "+v"(d) : "v"(a), "v"(b));
  return d;
}
#endif

// async global->LDS, 16B per lane; LDS dest = wave-uniform base + lane*16
DI void gload16(const void* g, void* l){
  __builtin_amdgcn_global_load_lds(
      (__attribute__((address_space(1))) void*)g,
      (__attribute__((address_space(3))) void*)l, 16, 0, 0);
}

// Fragment layouts (all 16-bit elems):
//   Qf/Kf[bh][tile][lane][16]: elem[kf*8+j] = M[tile*16 + (lane&15)][kf*32 + 8*(lane>>4) + j]
//   Vf  [bh][tile][lane][16]: elem[df*4+j] = V[tile*16 + 4*(lane>>4) + j][df*16 + (lane&15)]
//   ivf [b][tt][st][lane][4]: elem[r] = 1/S at (s = st*16 + (lane&15), t = tt*16 + 4*(lane>>4) + r)

// ---------------- cast f32 -> bf16 (4-wide) ----------------
__global__ void k_cast(const float* __restrict__ src, unsigned short* __restrict__ dst, int n4){
  int i = blockIdx.x*256 + threadIdx.x;
  if (i < n4){
    const float4 v = ((const float4*)src)[i];
    bfx4 o;
    o[0] = (short)f2bf(v.x); o[1] = (short)f2bf(v.y);
    o[2] = (short)f2bf(v.z); o[3] = (short)f2bf(v.w);
    *(bfx4*)(dst + (size_t)i*4) = o;
  }
}

// merged weight cast: 4 matrices (1024x1024 f32) -> contiguous bf16 dsts
__global__ void k_castw(const float* __restrict__ s0, const float* __restrict__ s1,
                        const float* __restrict__ s2, const float* __restrict__ s3,
                        unsigned short* __restrict__ dst){
  int i = blockIdx.x*256 + threadIdx.x;      // < 262144
  const float* src = (blockIdx.y==0) ? s0 : (blockIdx.y==1) ? s1 : (blockIdx.y==2) ? s2 : s3;
  const float4 v = ((const float4*)src)[i];
  bfx4 o;
  o[0] = (short)f2bf(v.x); o[1] = (short)f2bf(v.y);
  o[2] = (short)f2bf(v.z); o[3] = (short)f2bf(v.w);
  *(bfx4*)(dst + (size_t)blockIdx.y*1048576 + (size_t)i*4) = o;
}

// relk_bf: [272][64] zero-padded rows; relvT_bf: [64][288] = rel_v^T zero-padded cols
__global__ void k_relprep(const float* __restrict__ rlk, const float* __restrict__ rlv,
                          unsigned short* __restrict__ relk_bf, unsigned short* __restrict__ relvT_bf){
  int i = blockIdx.x*256 + threadIdx.x;
  if (i < 272*64){
    int r = i >> 6, d = i & 63;
    relk_bf[i] = (r < 257) ? f2bf(rlk[r*64 + d]) : (unsigned short)0;
  }
  if (i < 64*288){
    int d = i / 288, r = i % 288;
    relvT_bf[i] = (r < 257) ? f2bf(rlv[(size_t)r*64 + d]) : (unsigned short)0;
  }
}

// ---------------- QKV projections: counted-vmcnt double-buffered pipeline ----------------
__global__ __launch_bounds__(256, 3) void k_qkv(
    const unsigned short* __restrict__ xbf, const unsigned short* __restrict__ wqkv,
    unsigned short* __restrict__ Qf, unsigned short* __restrict__ Kf,
    unsigned short* __restrict__ Vf)
{
  __shared__ __align__(16) unsigned short smem[2][8192];   // 2 x 16 KB: A blocks 0-7, B blocks 8-15
  const int nt = blockIdx.x;
  const int b  = blockIdx.y;
  const int st = blockIdx.z;
  const int w = threadIdx.x >> 6, lane = threadIdx.x & 63;
  const int wr = w >> 1, wc = w & 1;
  const int p = lane & 15, g = lane >> 4;
  const int s0 = st*128;
  const int n0 = nt*128;
  const f4 fz = {0.f,0.f,0.f,0.f};
  f4 acc[4][4];
#pragma unroll
  for (int m=0;m<4;++m)
#pragma unroll
    for (int n=0;n<4;++n) acc[m][n] = fz;

  const int j0 = w*2, j1 = w*2 + 1;
  const unsigned short* gA = xbf  + (size_t)((s0 + p)*4 + b)*1024 + g*8;
  const unsigned short* gB = wqkv + (size_t)(n0 + p)*1024 + g*8;

  {
    unsigned short* d0 = &smem[0][0];
    gload16(gA + (size_t)j0*65536, d0 + j0*512);
    gload16(gA + (size_t)j1*65536, d0 + j1*512);
    gload16(gB + (size_t)j0*16384, d0 + 4096 + j0*512);
    gload16(gB + (size_t)j1*16384, d0 + 4096 + j1*512);
  }

  for (int it=0; it<32; ++it){
    const int cur = it & 1;
    if (it < 31){
      const int kn = (it+1)*32;
      unsigned short* dn = &smem[cur^1][0];
      gload16(gA + (size_t)j0*65536 + kn, dn + j0*512);
      gload16(gA + (size_t)j1*65536 + kn, dn + j1*512);
      gload16(gB + (size_t)j0*16384 + kn, dn + 4096 + j0*512);
      gload16(gB + (size_t)j1*16384 + kn, dn + 4096 + j1*512);
      asm volatile("s_waitcnt vmcnt(4)" ::: "memory");
    } else {
      asm volatile("s_waitcnt vmcnt(0)" ::: "memory");
    }
    __builtin_amdgcn_sched_barrier(0);
    __builtin_amdgcn_s_barrier();
    __builtin_amdgcn_sched_barrier(0);
    {
      const unsigned short* Ab = &smem[cur][0];
      bfx8 af[4], bfr[4];
#pragma unroll
      for (int m=0;m<4;++m) af[m] = *(const bfx8*)(Ab + (wr*4+m)*512 + lane*8);
#pragma unroll
      for (int n=0;n<4;++n) bfr[n] = *(const bfx8*)(Ab + 4096 + (wc*4+n)*512 + lane*8);
#pragma unroll
      for (int m=0;m<4;++m)
#pragma unroll
        for (int n=0;n<4;++n)
          acc[m][n] = mfma32(af[m], bfr[n], acc[m][n]);
    }
    __builtin_amdgcn_sched_barrier(0);
    __builtin_amdgcn_s_barrier();
    __builtin_amdgcn_sched_barrier(0);
  }

  const int n64 = n0 + wc*64;
  const int sec = n64 >> 10;            // 0 Q, 1 K, 2 V
  const int h = (n64 & 1023) >> 6;
  float* es = (float*)&smem[0][0] + w*1280;

  if (sec < 2){
    const float scl = (sec == 0) ? 0.125f : 1.0f;
    unsigned short* dst = (sec == 0) ? Qf : Kf;
#pragma unroll
    for (int m=0;m<4;++m){
#pragma unroll
      for (int n=0;n<4;++n)
#pragma unroll
        for (int r=0;r<4;++r)
          es[(4*g + r)*80 + 16*n + p] = acc[m][n][r] * scl;
      __syncthreads();
      f4 v0 = *(const f4*)&es[p*80 + 8*g];
      f4 v1 = *(const f4*)&es[p*80 + 8*g + 4];
      f4 v2 = *(const f4*)&es[p*80 + 32 + 8*g];
      f4 v3 = *(const f4*)&es[p*80 + 32 + 8*g + 4];
      bfx8 lo, hi;
#pragma unroll
      for (int j=0;j<4;++j){
        lo[j]   = (short)f2bf(v0[j]);
        lo[j+4] = (short)f2bf(v1[j]);
        hi[j]   = (short)f2bf(v2[j]);
        hi[j+4] = (short)f2bf(v3[j]);
      }
      size_t fb = ((size_t)(b*16 + h)*64 + (st*8 + wr*4 + m))*1024 + (size_t)lane*16;
      *(bfx8*)(dst + fb) = lo;
      *(bfx8*)(dst + fb + 8) = hi;
      __syncthreads();
    }
  } else {
#pragma unroll
    for (int m=0;m<4;++m){
#pragma unroll
      for (int n=0;n<4;++n)
        *(f4*)&es[(16*n + p)*20 + 4*g] = acc[m][n];
      __syncthreads();
      f4 vv0 = *(const f4*)&es[(p)*20 + 4*g];
      f4 vv1 = *(const f4*)&es[(16 + p)*20 + 4*g];
      f4 vv2 = *(const f4*)&es[(32 + p)*20 + 4*g];
      f4 vv3 = *(const f4*)&es[(48 + p)*20 + 4*g];
      bfx8 lo, hi;
#pragma unroll
      for (int j=0;j<4;++j){
        lo[j]   = (short)f2bf(vv0[j]);
        lo[j+4] = (short)f2bf(vv1[j]);
        hi[j]   = (short)f2bf(vv2[j]);
        hi[j+4] = (short)f2bf(vv3[j]);
      }
      size_t fb = ((size_t)(b*16 + h)*64 + (st*8 + wr*4 + m))*1024 + (size_t)lane*16;
      *(bfx8*)(Vf + fb) = lo;
      *(bfx8*)(Vf + fb + 8) = hi;
      __syncthreads();
    }
  }
}

// ---------------- Qr2 producer, write-coalesced: all 16 heads per block ----------------
__global__ __launch_bounds__(256) void k_qr(
    const unsigned short* __restrict__ Qf, const unsigned short* __restrict__ relk,
    unsigned short* __restrict__ Qr2)
{
  __shared__ __align__(16) unsigned short sst[16][16][24];
  const int bx = blockIdx.x;
  const int b  = bx & 3;
  const int st = (bx >> 2) & 63;
  const int uh = bx >> 8;
  const int w = threadIdx.x >> 6, lane = threadIdx.x & 63;
  const int p = lane & 15, g = lane >> 4;
  const int s0 = st << 4;
  const f4 fz = {0.f,0.f,0.f,0.f};

  bfx8 a0[4], a1[4];
#pragma unroll
  for (int hh=0; hh<4; ++hh){
    size_t fb = (((size_t)(b*16 + w*4 + hh))*64 + st)*1024 + (size_t)lane*16;
    a0[hh] = *(const bfx8*)(Qf + fb);
    a1[hh] = *(const bfx8*)(Qf + fb + 8);
  }

  const int c0 = uh ? 9 : 0;
  const int c1 = uh ? 17 : 9;
  const int so = threadIdx.x >> 4, uo = threadIdx.x & 15;

  for (int c=c0; c<c1; ++c){
    const int r0 = c << 4;
    bfx8 b0 = *(const bfx8*)(relk + (size_t)(r0 + p)*64 + 8*g);
    bfx8 b1 = *(const bfx8*)(relk + (size_t)(r0 + p)*64 + 32 + 8*g);
#pragma unroll
    for (int hh=0; hh<4; ++hh){
      f4 acc = mfma32(a1[hh], b1, mfma32(a0[hh], b0, fz));
#pragma unroll
      for (int r=0; r<4; ++r)
        sst[4*g + r][p][w*4 + hh] = f2bf(acc[r]);
    }
    __syncthreads();
    bfx8 v0 = *(const bfx8*)&sst[so][uo][0];
    bfx8 v1 = *(const bfx8*)&sst[so][uo][8];
    size_t ga = (((size_t)b*1024 + s0 + so)*272 + r0 + uo)*16;
    *(bfx8*)(Qr2 + ga) = v0;
    *(bfx8*)(Qr2 + ga + 8) = v1;
    __syncthreads();
  }
}

// ---------------- softmax denominator -> ivf (fragment layout, coalesced) ----------------
__global__ __launch_bounds__(256, 2) void k_s(
    const unsigned short* __restrict__ Qf, const unsigned short* __restrict__ Kf,
    const unsigned short* __restrict__ Qr2, float* __restrict__ ivf)
{
  const int pbid = blockIdx.x;            // (st<<6)|(ttg<<2)|b
  const int b   = pbid & 3;
  const int ttg = (pbid >> 2) & 15;
  const int st  = pbid >> 6;
  const int w = threadIdx.x >> 6, lane = threadIdx.x & 63;
  const int tt = ttg*4 + w;
  const int p = lane & 15, g = lane >> 4;
  const int s0 = st << 4, t0 = tt << 4;
  const int s = s0 + p;
  const f4 fz = {0.f,0.f,0.f,0.f};

  bfx8 rv[4][2];
#pragma unroll
  for (int r=0; r<4; ++r){
    int t = t0 + 4*g + r;
    int u = s - t + 128; u = u < 0 ? 0 : (u > 256 ? 256 : u);
    const unsigned short* q = Qr2 + (((size_t)b*1024 + s)*272 + u)*16;
    rv[r][0] = *(const bfx8*)q;
    rv[r][1] = *(const bfx8*)(q + 8);
  }

  const unsigned short* qbp = Qf + ((size_t)(b*16)*64 + st)*1024 + (size_t)lane*16;
  const unsigned short* kbp = Kf + ((size_t)(b*16)*64 + tt)*1024 + (size_t)lane*16;

  bfx8 qq[16][2], kk[16][2];
#define LOADH(H) { \
    qq[H][0] = *(const bfx8*)(qbp + (size_t)(H)*65536); \
    qq[H][1] = *(const bfx8*)(qbp + (size_t)(H)*65536 + 8); \
    kk[H][0] = *(const bfx8*)(kbp + (size_t)(H)*65536); \
    kk[H][1] = *(const bfx8*)(kbp + (size_t)(H)*65536 + 8); }

  LOADH(0) LOADH(1) LOADH(2) LOADH(3)

  f4 ps = fz;
#pragma unroll
  for (int h=0; h<16; ++h){
    if (h + 4 < 16){
      const int hn = h + 4;
      qq[hn][0] = *(const bfx8*)(qbp + (size_t)hn*65536);
      qq[hn][1] = *(const bfx8*)(qbp + (size_t)hn*65536 + 8);
      kk[hn][0] = *(const bfx8*)(kbp + (size_t)hn*65536);
      kk[hn][1] = *(const bfx8*)(kbp + (size_t)hn*65536 + 8);
    }
    f4 sc = mfma32(kk[h][1], qq[h][1], mfma32(kk[h][0], qq[h][0], fz));
    const int hg = h >> 3, hr = h & 7;
#pragma unroll
    for (int r=0; r<4; ++r)
      ps[r] += __expf(sc[r] + bf2f((unsigned short)rv[r][hg][hr]));
  }
#undef LOADH

  f4 inv;
#pragma unroll
  for (int r=0; r<4; ++r) inv[r] = 1.0f / ps[r];
  *(f4*)(ivf + (((size_t)(b*64 + tt)*64 + st)*64 + lane)*4) = inv;
}

// ---------------- fused attention: ALL 64 t-tiles per block (near+far merged) ----------------
// block = (b, st, hhalf); 4 waves x 2 heads. Near band scatters to skew; far tiles use qr0/qr1.
// Tail sums fully in-register; epilogue = PV + rel_v GEMM + tails -> out1 (no partials).
__global__ __launch_bounds__(256, 2) void k_attn(
    const unsigned short* __restrict__ Qf, const unsigned short* __restrict__ Kf,
    const unsigned short* __restrict__ Vf, const unsigned short* __restrict__ Qr2,
    const float* __restrict__ ivf, const unsigned short* __restrict__ relvT,
    const float* __restrict__ relv, unsigned short* __restrict__ out1)
{
  __shared__ __align__(16) unsigned short skew[128*264];   // 67,584 B
  const int pbid = blockIdx.x;
  const int xcd = pbid & 7;
  const int b = xcd >> 1;
  const int hhalf = (pbid >> 3) & 1;
  const int st = ((pbid >> 4) << 1) | (xcd & 1);
  const int s0 = st << 4;
  const int w = threadIdx.x >> 6;
  const int lane = threadIdx.x & 63;
  const int p = lane & 15, g = lane >> 4;
  const int s = s0 + p;
  const int hl0 = w * 2;                 // local head base (skew rows)
  const int h0 = hhalf*8 + hl0;          // global head base (memory)
  const f4 fz = {0.f,0.f,0.f,0.f};

  {
    unsigned* zp = (unsigned*)skew + w*4224;
    for (int i = lane; i < 4224; i += 64) zp[i] = 0u;
  }

  bfx8 qf[2][2]; float qr0[2], qr1[2];
#pragma unroll
  for (int hh=0; hh<2; ++hh){
    size_t qb = (((size_t)(b*16 + h0 + hh))*64 + st)*1024 + (size_t)lane*16;
    qf[hh][0] = *(const bfx8*)(Qf + qb);
    qf[hh][1] = *(const bfx8*)(Qf + qb + 8);
    qr0[hh] = bf2f(Qr2[(((size_t)b*1024 + s)*272 + 0)*16 + (h0+hh)]);
    qr1[hh] = bf2f(Qr2[(((size_t)b*1024 + s)*272 + 256)*16 + (h0+hh)]);
  }

  f4 o[2][4];
#pragma unroll
  for (int hh=0; hh<2; ++hh)
#pragma unroll
    for (int df=0; df<4; ++df) o[hh][df] = fz;

  float tl0[2] = {0.f,0.f};
  float tl1[2] = {0.f,0.f};

  const int tlo = (st-8 < 0) ? 0 : st-8;
  const int thi = (st+8 > 63) ? 63 : st+8;

  bfx8 kc[2][2]; bfx4 vc[2][4]; unsigned short qc[2][4]; f4 is;
  bfx8 kn[2][2]; bfx4 vn[2][4]; unsigned short qn[2][4]; f4 isn;

  // prologue: prefetch tile 0
#pragma unroll
  for (int hh=0; hh<2; ++hh){
    size_t bh = (size_t)(b*16 + h0 + hh);
    size_t fb = (bh*64 + 0)*1024 + (size_t)lane*16;
    kc[hh][0] = *(const bfx8*)(Kf + fb);
    kc[hh][1] = *(const bfx8*)(Kf + fb + 8);
#pragma unroll
    for (int df=0; df<4; ++df)
      vc[hh][df] = *(const bfx4*)(Vf + fb + df*4);
  }
  if (0 >= tlo){     // tile 0 in near band (st<=8)
#pragma unroll
    for (int hh=0; hh<2; ++hh)
#pragma unroll
      for (int r=0; r<4; ++r){
        int t = 4*g + r;
        int u = s - t + 128; u = u < 0 ? 0 : (u > 256 ? 256 : u);
        qc[hh][r] = Qr2[(((size_t)b*1024 + s)*272 + u)*16 + (h0+hh)];
      }
  }
  is = *(const f4*)(ivf + (((size_t)(b*64 + 0)*64 + st)*64 + lane)*4);

  for (int ti = 0; ti < 64; ++ti){
    const int t0 = ti << 4;
    const bool nearT = (ti >= tlo) && (ti <= thi);

    if (ti < 63){
      const int tn = ti + 1;
#pragma unroll
      for (int hh=0; hh<2; ++hh){
        size_t bh = (size_t)(b*16 + h0 + hh);
        size_t fb = (bh*64 + tn)*1024 + (size_t)lane*16;
        kn[hh][0] = *(const bfx8*)(Kf + fb);
        kn[hh][1] = *(const bfx8*)(Kf + fb + 8);
#pragma unroll
        for (int df=0; df<4; ++df)
          vn[hh][df] = *(const bfx4*)(Vf + fb + df*4);
      }
      if (tn >= tlo && tn <= thi){
#pragma unroll
        for (int hh=0; hh<2; ++hh)
#pragma unroll
          for (int r=0; r<4; ++r){
            int t = (tn<<4) + 4*g + r;
            int u = s - t + 128; u = u < 0 ? 0 : (u > 256 ? 256 : u);
            qn[hh][r] = Qr2[(((size_t)b*1024 + s)*272 + u)*16 + (h0+hh)];
          }
      }
      isn = *(const f4*)(ivf + (((size_t)(b*64 + tn)*64 + st)*64 + lane)*4);
    }

    if (nearT){
#pragma unroll
      for (int hh=0; hh<2; ++hh){
        f4 sc = mfma32(kc[hh][1], qf[hh][1], mfma32(kc[hh][0], qf[hh][0], fz));
        f4 at;
#pragma unroll
        for (int r=0; r<4; ++r) at[r] = __expf(sc[r] + bf2f(qc[hh][r])) * is[r];
        const int row = (hl0 + hh)*16 + p;
#pragma unroll
        for (int r=0; r<4; ++r){
          int t = t0 + 4*g + r;
          int u = s - t + 128;
          float a = at[r];
          if (u <= 0) tl0[hh] += a;
          else if (u >= 256) tl1[hh] += a;
          else skew[row*264 + u] = f2bf(a);
        }
        bfx4 pk;
#pragma unroll
        for (int r=0; r<4; ++r) pk[r] = (short)f2bf(at[r]);
#pragma unroll
        for (int df=0; df<4; ++df)
          o[hh][df] = mfma16(vc[hh][df], pk, o[hh][df]);
      }
    } else {
      const bool hiSide = (ti < st);     // u >= 256 side
#pragma unroll
      for (int hh=0; hh<2; ++hh){
        f4 sc = mfma32(kc[hh][1], qf[hh][1], mfma32(kc[hh][0], qf[hh][0], fz));
        const float qa = hiSide ? qr1[hh] : qr0[hh];
        f4 at;
#pragma unroll
        for (int r=0; r<4; ++r) at[r] = __expf(sc[r] + qa) * is[r];
        float tsum = at[0] + at[1] + at[2] + at[3];
        if (hiSide) tl1[hh] += tsum; else tl0[hh] += tsum;
        bfx4 pk;
#pragma unroll
        for (int r=0; r<4; ++r) pk[r] = (short)f2bf(at[r]);
#pragma unroll
        for (int df=0; df<4; ++df)
          o[hh][df] = mfma16(vc[hh][df], pk, o[hh][df]);
      }
    }

    if (ti < 63){
#pragma unroll
      for (int hh=0; hh<2; ++hh){
#pragma unroll
        for (int kf=0; kf<2; ++kf) kc[hh][kf] = kn[hh][kf];
#pragma unroll
        for (int df=0; df<4; ++df) vc[hh][df] = vn[hh][df];
#pragma unroll
        for (int r=0; r<4; ++r) qc[hh][r] = qn[hh][r];
      }
      is = isn;
    }
  }

  __syncthreads();

  // ---- fused out2 = rel_v^T @ skew (own-wave rows only; local head rows) ----
  f4 acc2[2][4];
#pragma unroll
  for (int hh=0; hh<2; ++hh)
#pragma unroll
    for (int df=0; df<4; ++df) acc2[hh][df] = fz;
#pragma unroll
  for (int k0=0; k0<256; k0+=32){
    bfx8 bb0 = *(const bfx8*)&skew[(hl0*16 + p)*264 + k0 + 8*g];
    bfx8 bb1 = *(const bfx8*)&skew[((hl0+1)*16 + p)*264 + k0 + 8*g];
#pragma unroll
    for (int df=0; df<4; ++df){
      bfx8 a = *(const bfx8*)(relvT + (size_t)(df*16 + p)*288 + k0 + 8*g);
      acc2[0][df] = mfma32(a, bb0, acc2[0][df]);
      acc2[1][df] = mfma32(a, bb1, acc2[1][df]);
    }
  }

  f4 rv0[4], rv1[4];
#pragma unroll
  for (int df=0; df<4; ++df){
    rv0[df] = *(const f4*)(relv + df*16 + 4*g);
    rv1[df] = *(const f4*)(relv + 16384 + df*16 + 4*g);
  }
#pragma unroll
  for (int hh=0; hh<2; ++hh){
    float tv0 = tl0[hh];
    tv0 += __shfl_xor(tv0, 16, 64);
    tv0 += __shfl_xor(tv0, 32, 64);
    float tv1 = tl1[hh];
    tv1 += __shfl_xor(tv1, 16, 64);
    tv1 += __shfl_xor(tv1, 32, 64);
#pragma unroll
    for (int df=0; df<4; ++df)
#pragma unroll
      for (int r=0; r<4; ++r)
        o[hh][df][r] += acc2[hh][df][r] + tv0*rv0[df][r] + tv1*rv1[df][r];
  }

  __syncthreads();

  float* slabBase = (float*)skew;
  float (*tb)[68] = (float(*)[68])(slabBase + w*(16*68));
#pragma unroll
  for (int hh=0; hh<2; ++hh){
#pragma unroll
    for (int df=0; df<4; ++df)
      *(f4*)&tb[p][df*16 + 4*g] = o[hh][df];
    __syncthreads();
    const int srow = lane >> 2, quad = lane & 3;
    f4 r0 = *(const f4*)&tb[srow][quad*16 + 0];
    f4 r1 = *(const f4*)&tb[srow][quad*16 + 4];
    f4 r2 = *(const f4*)&tb[srow][quad*16 + 8];
    f4 r3 = *(const f4*)&tb[srow][quad*16 + 12];
    size_t addr = ((size_t)b*1024 + s0 + srow)*1024 + (h0+hh)*64 + quad*16;
    bfx8 pa, pb;
#pragma unroll
    for (int j=0; j<4; ++j){
      pa[j]   = (short)f2bf(r0[j]);
      pa[j+4] = (short)f2bf(r1[j]);
      pb[j]   = (short)f2bf(r2[j]);
      pb[j+4] = (short)f2bf(r3[j]);
    }
    *(bfx8*)(out1 + addr) = pa;
    *(bfx8*)(out1 + addr + 8) = pb;
    __syncthreads();
  }
}

// ---------------- final projection: counted-vmcnt double-buffered pipeline ----------------
__global__ __launch_bounds__(256) void k_wo(
    const unsigned short* __restrict__ out1, const unsigned short* __restrict__ wo,
    const float* __restrict__ bo, float* __restrict__ dout)
{
  __shared__ __align__(16) unsigned short smem[2][6144];
  const int nt = blockIdx.x;
  const int mt = blockIdx.y;
  const int w = threadIdx.x >> 6, lane = threadIdx.x & 63;
  const int wr = w >> 1, wc = w & 1;
  const int p = lane & 15, g = lane >> 4;
  const int m0 = mt*64, n0 = nt*128;
  const f4 fz = {0.f,0.f,0.f,0.f};
  f4 acc[2][4];
#pragma unroll
  for (int m=0;m<2;++m)
#pragma unroll
    for (int n=0;n<4;++n) acc[m][n] = fz;

  const int j0 = w*2, j1 = w*2 + 1;
  const unsigned short* gA = out1 + (size_t)(m0 + p)*1024 + g*8;
  const unsigned short* gB = wo   + (size_t)(n0 + p)*1024 + g*8;

  {
    unsigned short* d0 = &smem[0][0];
    gload16(gA + (size_t)w*16384, d0 + w*512);
    gload16(gB + (size_t)j0*16384, d0 + 2048 + j0*512);
    gload16(gB + (size_t)j1*16384, d0 + 2048 + j1*512);
  }

  for (int it=0; it<32; ++it){
    const int cur = it & 1;
    if (it < 31){
      const int kn = (it+1)*32;
      unsigned short* dn = &smem[cur^1][0];
      gload16(gA + (size_t)w*16384 + kn, dn + w*512);
      gload16(gB + (size_t)j0*16384 + kn, dn + 2048 + j0*512);
      gload16(gB + (size_t)j1*16384 + kn, dn + 2048 + j1*512);
      asm volatile("s_waitcnt vmcnt(3)" ::: "memory");
    } else {
      asm volatile("s_waitcnt vmcnt(0)" ::: "memory");
    }
    __builtin_amdgcn_sched_barrier(0);
    __builtin_amdgcn_s_barrier();
    __builtin_amdgcn_sched_barrier(0);
    {
      const unsigned short* Ab = &smem[cur][0];
      bfx8 af[2], bfr[4];
#pragma unroll
      for (int m=0;m<2;++m) af[m] = *(const bfx8*)(Ab + (wr*2+m)*512 + lane*8);
#pragma unroll
      for (int n=0;n<4;++n) bfr[n] = *(const bfx8*)(Ab + 2048 + (wc*4+n)*512 + lane*8);
#pragma unroll
      for (int m=0;m<2;++m)
#pragma unroll
        for (int n=0;n<4;++n)
          acc[m][n] = mfma32(af[m], bfr[n], acc[m][n]);
    }
    __builtin_amdgcn_sched_barrier(0);
    __builtin_amdgcn_s_barrier();
    __builtin_amdgcn_sched_barrier(0);
  }

#pragma unroll
  for (int n=0;n<4;++n){
    const int col = n0 + wc*64 + n*16 + p;
    const float bias = bo[col];
#pragma unroll
    for (int m=0;m<2;++m)
#pragma unroll
      for (int r=0;r<4;++r){
        int row = m0 + wr*32 + m*16 + 4*g + r;
        int bb = row >> 10, s = row & 1023;
        dout[((size_t)s*4 + bb)*1024 + col] = acc[m][n][r] + bias;
      }
  }
}

extern "C" void kernel_launch(void* const* d_in, const int* in_sizes, int n_in,
                              void* d_out, int out_size, void* d_ws, size_t ws_size,
                              hipStream_t stream){
  const float* x   = (const float*)d_in[0];
  const float* wq  = (const float*)d_in[1];
  const float* wk  = (const float*)d_in[2];
  const float* wv  = (const float*)d_in[3];
  const float* wo  = (const float*)d_in[4];
  const float* bo  = (const float*)d_in[5];
  const float* rlk = (const float*)d_in[6];
  const float* rlv = (const float*)d_in[7];
  char* ws = (char*)d_ws;

  unsigned short* x_bf    = (unsigned short*)(ws + 0);
  unsigned short* wq_bf   = (unsigned short*)(ws + 8388608);   // [wq|wk|wv|wo] contiguous
  unsigned short* relk_bf = (unsigned short*)(ws + 16777216);
  unsigned short* relvT_bf= (unsigned short*)(ws + 16812032);
  unsigned short* Qf      = (unsigned short*)(ws + 16848896);   // fragment layout
  unsigned short* Kf      = (unsigned short*)(ws + 25237504);   // fragment layout
  unsigned short* Vf      = (unsigned short*)(ws + 33626112);   // fragment layout
  unsigned short* Qr2     = (unsigned short*)(ws + 42014720);   // 35.65 MB -> 77666304
  unsigned short* out1    = (unsigned short*)(ws + 113317888);  // 8 MB
  float*          ivf     = (float*)        (ws + 121706496);  // 16 MB -> 138483712
  unsigned short* wo_bf   = (unsigned short*)(ws + 14680064);

  k_cast<<<4096, 256, 0, stream>>>(x, x_bf, 1048576);
  k_castw<<<dim3(1024,4), 256, 0, stream>>>(wq, wk, wv, wo, wq_bf);
  k_relprep<<<72, 256, 0, stream>>>(rlk, rlv, relk_bf, relvT_bf);

  k_qkv<<<dim3(24,4,8), 256, 0, stream>>>(x_bf, wq_bf, Qf, Kf, Vf);
  k_qr<<<512, 256, 0, stream>>>(Qf, relk_bf, Qr2);

  k_s   <<<4096, 256, 0, stream>>>(Qf, Kf, Qr2, ivf);
  k_attn<<<512, 256, 0, stream>>>(Qf, Kf, Vf, Qr2, ivf, relvT_bf, rlv, out1);
  k_wo<<<dim3(8,64), 256, 0, stream>>>(out1, wo_bf, bo, (float*)d_out);
}

// Round 15
// 223.935 us; speedup vs baseline: 1.1116x; 1.0118x over previous
//
#include <hip/hip_runtime.h>
#include <stdint.h>

#define DI __device__ __forceinline__

typedef __attribute__((ext_vector_type(8))) short bfx8;
typedef __attribute__((ext_vector_type(4))) short bfx4;
typedef __attribute__((ext_vector_type(4))) float f4;

DI unsigned short f2bf(float x){
  unsigned u = __float_as_uint(x);
  u = (u + 0x7FFFu + ((u >> 16) & 1u)) >> 16;
  return (unsigned short)u;
}
DI float bf2f(unsigned short h){ return __uint_as_float(((unsigned)h) << 16); }

DI f4 mfma32(bfx8 a, bfx8 b, f4 c){
  return __builtin_amdgcn_mfma_f32_16x16x32_bf16(a, b, c, 0, 0, 0);
}
#if __has_builtin(__builtin_amdgcn_mfma_f32_16x16x16bf16_1k)
DI f4 mfma16(bfx4 a, bfx4 b, f4 c){
  return __builtin_amdgcn_mfma_f32_16x16x16bf16_1k(a, b, c, 0, 0, 0);
}
#else
DI f4 mfma16(bfx4 a, bfx4 b, f4 c){
  f4 d = c;
  asm volatile("v_mfma_f32_16x16x16_bf16 %0, %1, %2, %0" : "+v"(d) : "v"(a), "v"(b));
  return d;
}
#endif

DI bfx4 lo4(bfx8 v){ bfx4 r; r[0]=v[0]; r[1]=v[1]; r[2]=v[2]; r[3]=v[3]; return r; }
DI bfx4 hi4(bfx8 v){ bfx4 r; r[0]=v[4]; r[1]=v[5]; r[2]=v[6]; r[3]=v[7]; return r; }

// async global->LDS, 16B per lane; LDS dest = wave-uniform base + lane*16
DI void gload16(const void* g, void* l){
  __builtin_amdgcn_global_load_lds(
      (__attribute__((address_space(1))) void*)g,
      (__attribute__((address_space(3))) void*)l, 16, 0, 0);
}

// Fragment layouts (all 16-bit elems):
//   Qf/Kf[bh][tile][lane][16]: elem[kf*8+j] = M[tile*16 + (lane&15)][kf*32 + 8*(lane>>4) + j]
//   Vf  [bh][tile][lane][16]: elem[df*4+j] = V[tile*16 + 4*(lane>>4) + j][df*16 + (lane&15)]
//   ivf [b][tt][st][lane][4]: elem[r] = 1/S at (s = st*16 + (lane&15), t = tt*16 + 4*(lane>>4) + r)

// ---------------- cast f32 -> bf16 (4-wide) ----------------
__global__ void k_cast(const float* __restrict__ src, unsigned short* __restrict__ dst, int n4){
  int i = blockIdx.x*256 + threadIdx.x;
  if (i < n4){
    const float4 v = ((const float4*)src)[i];
    bfx4 o;
    o[0] = (short)f2bf(v.x); o[1] = (short)f2bf(v.y);
    o[2] = (short)f2bf(v.z); o[3] = (short)f2bf(v.w);
    *(bfx4*)(dst + (size_t)i*4) = o;
  }
}

// merged weight cast: 4 matrices (1024x1024 f32) -> contiguous bf16 dsts
__global__ void k_castw(const float* __restrict__ s0, const float* __restrict__ s1,
                        const float* __restrict__ s2, const float* __restrict__ s3,
                        unsigned short* __restrict__ dst){
  int i = blockIdx.x*256 + threadIdx.x;      // < 262144
  const float* src = (blockIdx.y==0) ? s0 : (blockIdx.y==1) ? s1 : (blockIdx.y==2) ? s2 : s3;
  const float4 v = ((const float4*)src)[i];
  bfx4 o;
  o[0] = (short)f2bf(v.x); o[1] = (short)f2bf(v.y);
  o[2] = (short)f2bf(v.z); o[3] = (short)f2bf(v.w);
  *(bfx4*)(dst + (size_t)blockIdx.y*1048576 + (size_t)i*4) = o;
}

// relk_bf: [272][64] zero-padded rows; relvT_bf: [64][288] = rel_v^T zero-padded cols
__global__ void k_relprep(const float* __restrict__ rlk, const float* __restrict__ rlv,
                          unsigned short* __restrict__ relk_bf, unsigned short* __restrict__ relvT_bf){
  int i = blockIdx.x*256 + threadIdx.x;
  if (i < 272*64){
    int r = i >> 6, d = i & 63;
    relk_bf[i] = (r < 257) ? f2bf(rlk[r*64 + d]) : (unsigned short)0;
  }
  if (i < 64*288){
    int d = i / 288, r = i % 288;
    relvT_bf[i] = (r < 257) ? f2bf(rlv[(size_t)r*64 + d]) : (unsigned short)0;
  }
}

// ---------------- QKV projections: counted-vmcnt double-buffered pipeline ----------------
__global__ __launch_bounds__(256, 3) void k_qkv(
    const unsigned short* __restrict__ xbf, const unsigned short* __restrict__ wqkv,
    unsigned short* __restrict__ Qf, unsigned short* __restrict__ Kf,
    unsigned short* __restrict__ Vf)
{
  __shared__ __align__(16) unsigned short smem[2][8192];   // 2 x 16 KB: A blocks 0-7, B blocks 8-15
  const int nt = blockIdx.x;
  const int b  = blockIdx.y;
  const int st = blockIdx.z;
  const int w = threadIdx.x >> 6, lane = threadIdx.x & 63;
  const int wr = w >> 1, wc = w & 1;
  const int p = lane & 15, g = lane >> 4;
  const int s0 = st*128;
  const int n0 = nt*128;
  const f4 fz = {0.f,0.f,0.f,0.f};
  f4 acc[4][4];
#pragma unroll
  for (int m=0;m<4;++m)
#pragma unroll
    for (int n=0;n<4;++n) acc[m][n] = fz;

  const int j0 = w*2, j1 = w*2 + 1;
  const unsigned short* gA = xbf  + (size_t)((s0 + p)*4 + b)*1024 + g*8;
  const unsigned short* gB = wqkv + (size_t)(n0 + p)*1024 + g*8;

  {
    unsigned short* d0 = &smem[0][0];
    gload16(gA + (size_t)j0*65536, d0 + j0*512);
    gload16(gA + (size_t)j1*65536, d0 + j1*512);
    gload16(gB + (size_t)j0*16384, d0 + 4096 + j0*512);
    gload16(gB + (size_t)j1*16384, d0 + 4096 + j1*512);
  }

  for (int it=0; it<32; ++it){
    const int cur = it & 1;
    if (it < 31){
      const int kn = (it+1)*32;
      unsigned short* dn = &smem[cur^1][0];
      gload16(gA + (size_t)j0*65536 + kn, dn + j0*512);
      gload16(gA + (size_t)j1*65536 + kn, dn + j1*512);
      gload16(gB + (size_t)j0*16384 + kn, dn + 4096 + j0*512);
      gload16(gB + (size_t)j1*16384 + kn, dn + 4096 + j1*512);
      asm volatile("s_waitcnt vmcnt(4)" ::: "memory");
    } else {
      asm volatile("s_waitcnt vmcnt(0)" ::: "memory");
    }
    __builtin_amdgcn_sched_barrier(0);
    __builtin_amdgcn_s_barrier();
    __builtin_amdgcn_sched_barrier(0);
    {
      const unsigned short* Ab = &smem[cur][0];
      bfx8 af[4], bfr[4];
#pragma unroll
      for (int m=0;m<4;++m) af[m] = *(const bfx8*)(Ab + (wr*4+m)*512 + lane*8);
#pragma unroll
      for (int n=0;n<4;++n) bfr[n] = *(const bfx8*)(Ab + 4096 + (wc*4+n)*512 + lane*8);
#pragma unroll
      for (int m=0;m<4;++m)
#pragma unroll
        for (int n=0;n<4;++n)
          acc[m][n] = mfma32(af[m], bfr[n], acc[m][n]);
    }
    __builtin_amdgcn_sched_barrier(0);
    __builtin_amdgcn_s_barrier();
    __builtin_amdgcn_sched_barrier(0);
  }

  const int n64 = n0 + wc*64;
  const int sec = n64 >> 10;            // 0 Q, 1 K, 2 V
  const int h = (n64 & 1023) >> 6;
  float* es = (float*)&smem[0][0] + w*1280;

  if (sec < 2){
    const float scl = (sec == 0) ? 0.125f : 1.0f;
    unsigned short* dst = (sec == 0) ? Qf : Kf;
#pragma unroll
    for (int m=0;m<4;++m){
#pragma unroll
      for (int n=0;n<4;++n)
#pragma unroll
        for (int r=0;r<4;++r)
          es[(4*g + r)*80 + 16*n + p] = acc[m][n][r] * scl;
      __syncthreads();
      f4 v0 = *(const f4*)&es[p*80 + 8*g];
      f4 v1 = *(const f4*)&es[p*80 + 8*g + 4];
      f4 v2 = *(const f4*)&es[p*80 + 32 + 8*g];
      f4 v3 = *(const f4*)&es[p*80 + 32 + 8*g + 4];
      bfx8 lo, hi;
#pragma unroll
      for (int j=0;j<4;++j){
        lo[j]   = (short)f2bf(v0[j]);
        lo[j+4] = (short)f2bf(v1[j]);
        hi[j]   = (short)f2bf(v2[j]);
        hi[j+4] = (short)f2bf(v3[j]);
      }
      size_t fb = ((size_t)(b*16 + h)*64 + (st*8 + wr*4 + m))*1024 + (size_t)lane*16;
      *(bfx8*)(dst + fb) = lo;
      *(bfx8*)(dst + fb + 8) = hi;
      __syncthreads();
    }
  } else {
#pragma unroll
    for (int m=0;m<4;++m){
#pragma unroll
      for (int n=0;n<4;++n)
        *(f4*)&es[(16*n + p)*20 + 4*g] = acc[m][n];
      __syncthreads();
      f4 vv0 = *(const f4*)&es[(p)*20 + 4*g];
      f4 vv1 = *(const f4*)&es[(16 + p)*20 + 4*g];
      f4 vv2 = *(const f4*)&es[(32 + p)*20 + 4*g];
      f4 vv3 = *(const f4*)&es[(48 + p)*20 + 4*g];
      bfx8 lo, hi;
#pragma unroll
      for (int j=0;j<4;++j){
        lo[j]   = (short)f2bf(vv0[j]);
        lo[j+4] = (short)f2bf(vv1[j]);
        hi[j]   = (short)f2bf(vv2[j]);
        hi[j+4] = (short)f2bf(vv3[j]);
      }
      size_t fb = ((size_t)(b*16 + h)*64 + (st*8 + wr*4 + m))*1024 + (size_t)lane*16;
      *(bfx8*)(Vf + fb) = lo;
      *(bfx8*)(Vf + fb + 8) = hi;
      __syncthreads();
    }
  }
}

// ---------------- Qr2 producer, write-coalesced: all 16 heads per block ----------------
__global__ __launch_bounds__(256) void k_qr(
    const unsigned short* __restrict__ Qf, const unsigned short* __restrict__ relk,
    unsigned short* __restrict__ Qr2)
{
  __shared__ __align__(16) unsigned short sst[16][16][24];
  const int bx = blockIdx.x;
  const int b  = bx & 3;
  const int st = (bx >> 2) & 63;
  const int uh = bx >> 8;
  const int w = threadIdx.x >> 6, lane = threadIdx.x & 63;
  const int p = lane & 15, g = lane >> 4;
  const int s0 = st << 4;
  const f4 fz = {0.f,0.f,0.f,0.f};

  bfx8 a0[4], a1[4];
#pragma unroll
  for (int hh=0; hh<4; ++hh){
    size_t fb = (((size_t)(b*16 + w*4 + hh))*64 + st)*1024 + (size_t)lane*16;
    a0[hh] = *(const bfx8*)(Qf + fb);
    a1[hh] = *(const bfx8*)(Qf + fb + 8);
  }

  const int c0 = uh ? 9 : 0;
  const int c1 = uh ? 17 : 9;
  const int so = threadIdx.x >> 4, uo = threadIdx.x & 15;

  for (int c=c0; c<c1; ++c){
    const int r0 = c << 4;
    bfx8 b0 = *(const bfx8*)(relk + (size_t)(r0 + p)*64 + 8*g);
    bfx8 b1 = *(const bfx8*)(relk + (size_t)(r0 + p)*64 + 32 + 8*g);
#pragma unroll
    for (int hh=0; hh<4; ++hh){
      f4 acc = mfma32(a1[hh], b1, mfma32(a0[hh], b0, fz));
#pragma unroll
      for (int r=0; r<4; ++r)
        sst[4*g + r][p][w*4 + hh] = f2bf(acc[r]);
    }
    __syncthreads();
    bfx8 v0 = *(const bfx8*)&sst[so][uo][0];
    bfx8 v1 = *(const bfx8*)&sst[so][uo][8];
    size_t ga = (((size_t)b*1024 + s0 + so)*272 + r0 + uo)*16;
    *(bfx8*)(Qr2 + ga) = v0;
    *(bfx8*)(Qr2 + ga + 8) = v1;
    __syncthreads();
  }
}

// ---------------- softmax denominator -> ivf; LDS-staged Q/K shared across 8 waves ----------------
// block = (b, st-pair, tt-quad); 8 waves = 2 st x 4 tt. Per head: Q(2 frags)+K(4 frags) staged
// ONCE per block via gload16 double-buffer (24 KB) -> ~2.6x less fragment traffic than per-wave loads.
__global__ __launch_bounds__(512, 4) void k_s(
    const unsigned short* __restrict__ Qf, const unsigned short* __restrict__ Kf,
    const unsigned short* __restrict__ Qr2, float* __restrict__ ivf)
{
  __shared__ __align__(16) unsigned short qs[2][2][1024];   // [buf][st_local][2KB frag]
  __shared__ __align__(16) unsigned short ks[2][4][1024];   // [buf][tt_local][2KB frag]
  const int pbid = blockIdx.x;            // (stg<<6)|(ttg<<2)|b
  const int b   = pbid & 3;
  const int ttg = (pbid >> 2) & 15;
  const int stg = pbid >> 6;              // 0..31
  const int w = threadIdx.x >> 6, lane = threadIdx.x & 63;
  const int stl = w >> 2, ttl = w & 3;
  const int st = stg*2 + stl;
  const int tt = ttg*4 + ttl;
  const int p = lane & 15, g = lane >> 4;
  const int s = (st << 4) + p;
  const int t0 = tt << 4;
  const f4 fz = {0.f,0.f,0.f,0.f};

  // rel addends for all 16 heads, per r (head-last Qr2 layout)
  bfx8 rv[4][2];
#pragma unroll
  for (int r=0; r<4; ++r){
    int t = t0 + 4*g + r;
    int u = s - t + 128; u = u < 0 ? 0 : (u > 256 ? 256 : u);
    const unsigned short* q = Qr2 + (((size_t)b*1024 + s)*272 + u)*16;
    rv[r][0] = *(const bfx8*)q;
    rv[r][1] = *(const bfx8*)(q + 8);
  }

  // staging roles: w0/w1 -> Q[st_local=w]; w4..w7 -> K[tt_local=w-4]; w2/w3 idle
  const bool stager = (w <= 1) || (w >= 4);
  const unsigned short* gsrc =
      (w <= 1) ? (Qf + ((size_t)(b*16)*64 + (stg*2 + w))*1024)
               : (Kf + ((size_t)(b*16)*64 + (ttg*4 + (w & 3)))*1024);
  unsigned short* ldst[2];
  ldst[0] = (w <= 1) ? &qs[0][w][0] : &ks[0][w & 3][0];
  ldst[1] = (w <= 1) ? &qs[1][w][0] : &ks[1][w & 3][0];

  // prologue: head 0 -> buf 0
  if (stager){
    gload16(gsrc + (size_t)lane*8, ldst[0]);
    gload16(gsrc + 512 + (size_t)lane*8, ldst[0] + 512);
    asm volatile("s_waitcnt vmcnt(0)" ::: "memory");
  }
  __builtin_amdgcn_sched_barrier(0);
  __builtin_amdgcn_s_barrier();
  __builtin_amdgcn_sched_barrier(0);

  f4 ps = fz;
#pragma unroll
  for (int h=0; h<16; ++h){
    const int buf = h & 1;
    if (h < 15 && stager){
      unsigned short* ld = ldst[buf ^ 1];
      gload16(gsrc + (size_t)(h+1)*65536 + (size_t)lane*8, ld);
      gload16(gsrc + (size_t)(h+1)*65536 + 512 + (size_t)lane*8, ld + 512);
    }
    {
      const unsigned short* qb = &qs[buf][stl][lane*16];
      const unsigned short* kb = &ks[buf][ttl][lane*16];
      bfx8 q0 = *(const bfx8*)qb;
      bfx8 q1 = *(const bfx8*)(qb + 8);
      bfx8 k0 = *(const bfx8*)kb;
      bfx8 k1 = *(const bfx8*)(kb + 8);
      f4 sc = mfma32(k1, q1, mfma32(k0, q0, fz));
      const int hg = h >> 3, hr = h & 7;
#pragma unroll
      for (int r=0; r<4; ++r)
        ps[r] += __expf(sc[r] + bf2f((unsigned short)rv[r][hg][hr]));
    }
    if (h < 15){
      if (stager) asm volatile("s_waitcnt vmcnt(0)" ::: "memory");
      __builtin_amdgcn_sched_barrier(0);
      __builtin_amdgcn_s_barrier();
      __builtin_amdgcn_sched_barrier(0);
    }
  }

  f4 inv;
#pragma unroll
  for (int r=0; r<4; ++r) inv[r] = 1.0f / ps[r];
  *(f4*)(ivf + (((size_t)(b*64 + tt)*64 + st)*64 + lane)*4) = inv;
}

// ---------------- fused attention: ALL 64 t-tiles per block (near+far merged) ----------------
__global__ __launch_bounds__(256, 2) void k_attn(
    const unsigned short* __restrict__ Qf, const unsigned short* __restrict__ Kf,
    const unsigned short* __restrict__ Vf, const unsigned short* __restrict__ Qr2,
    const float* __restrict__ ivf, const unsigned short* __restrict__ relvT,
    const float* __restrict__ relv, unsigned short* __restrict__ out1)
{
  __shared__ __align__(16) unsigned short skew[128*264];   // 67,584 B
  const int pbid = blockIdx.x;
  const int xcd = pbid & 7;
  const int b = xcd >> 1;
  const int hhalf = (pbid >> 3) & 1;
  const int st = ((pbid >> 4) << 1) | (xcd & 1);
  const int s0 = st << 4;
  const int w = threadIdx.x >> 6;
  const int lane = threadIdx.x & 63;
  const int p = lane & 15, g = lane >> 4;
  const int s = s0 + p;
  const int hl0 = w * 2;                 // local head base (skew rows)
  const int h0 = hhalf*8 + hl0;          // global head base (memory)
  const f4 fz = {0.f,0.f,0.f,0.f};

  {
    unsigned* zp = (unsigned*)skew + w*4224;
    for (int i = lane; i < 4224; i += 64) zp[i] = 0u;
  }

  bfx8 qf[2][2]; float qr0[2], qr1[2];
#pragma unroll
  for (int hh=0; hh<2; ++hh){
    size_t qb = (((size_t)(b*16 + h0 + hh))*64 + st)*1024 + (size_t)lane*16;
    qf[hh][0] = *(const bfx8*)(Qf + qb);
    qf[hh][1] = *(const bfx8*)(Qf + qb + 8);
    qr0[hh] = bf2f(Qr2[(((size_t)b*1024 + s)*272 + 0)*16 + (h0+hh)]);
    qr1[hh] = bf2f(Qr2[(((size_t)b*1024 + s)*272 + 256)*16 + (h0+hh)]);
  }

  f4 o[2][4];
#pragma unroll
  for (int hh=0; hh<2; ++hh)
#pragma unroll
    for (int df=0; df<4; ++df) o[hh][df] = fz;

  float tl0[2] = {0.f,0.f};
  float tl1[2] = {0.f,0.f};

  const int tlo = (st-8 < 0) ? 0 : st-8;
  const int thi = (st+8 > 63) ? 63 : st+8;

  bfx8 kc[2][2]; bfx8 vc8[2][2]; unsigned short qc[2][4]; f4 is;
  bfx8 kn[2][2]; bfx8 vn8[2][2]; unsigned short qn[2][4]; f4 isn;

  // prologue: prefetch tile 0
#pragma unroll
  for (int hh=0; hh<2; ++hh){
    size_t bh = (size_t)(b*16 + h0 + hh);
    size_t fb = (bh*64 + 0)*1024 + (size_t)lane*16;
    kc[hh][0] = *(const bfx8*)(Kf + fb);
    kc[hh][1] = *(const bfx8*)(Kf + fb + 8);
    vc8[hh][0] = *(const bfx8*)(Vf + fb);
    vc8[hh][1] = *(const bfx8*)(Vf + fb + 8);
  }
  if (0 >= tlo){     // tile 0 in near band (st<=8)
#pragma unroll
    for (int hh=0; hh<2; ++hh)
#pragma unroll
      for (int r=0; r<4; ++r){
        int t = 4*g + r;
        int u = s - t + 128; u = u < 0 ? 0 : (u > 256 ? 256 : u);
        qc[hh][r] = Qr2[(((size_t)b*1024 + s)*272 + u)*16 + (h0+hh)];
      }
  }
  is = *(const f4*)(ivf + (((size_t)(b*64 + 0)*64 + st)*64 + lane)*4);

  for (int ti = 0; ti < 64; ++ti){
    const int t0 = ti << 4;
    const bool nearT = (ti >= tlo) && (ti <= thi);

    if (ti < 63){
      const int tn = ti + 1;
#pragma unroll
      for (int hh=0; hh<2; ++hh){
        size_t bh = (size_t)(b*16 + h0 + hh);
        size_t fb = (bh*64 + tn)*1024 + (size_t)lane*16;
        kn[hh][0] = *(const bfx8*)(Kf + fb);
        kn[hh][1] = *(const bfx8*)(Kf + fb + 8);
        vn8[hh][0] = *(const bfx8*)(Vf + fb);
        vn8[hh][1] = *(const bfx8*)(Vf + fb + 8);
      }
      if (tn >= tlo && tn <= thi){
#pragma unroll
        for (int hh=0; hh<2; ++hh)
#pragma unroll
          for (int r=0; r<4; ++r){
            int t = (tn<<4) + 4*g + r;
            int u = s - t + 128; u = u < 0 ? 0 : (u > 256 ? 256 : u);
            qn[hh][r] = Qr2[(((size_t)b*1024 + s)*272 + u)*16 + (h0+hh)];
          }
      }
      isn = *(const f4*)(ivf + (((size_t)(b*64 + tn)*64 + st)*64 + lane)*4);
    }

    if (nearT){
#pragma unroll
      for (int hh=0; hh<2; ++hh){
        f4 sc = mfma32(kc[hh][1], qf[hh][1], mfma32(kc[hh][0], qf[hh][0], fz));
        f4 at;
#pragma unroll
        for (int r=0; r<4; ++r) at[r] = __expf(sc[r] + bf2f(qc[hh][r])) * is[r];
        const int row = (hl0 + hh)*16 + p;
#pragma unroll
        for (int r=0; r<4; ++r){
          int t = t0 + 4*g + r;
          int u = s - t + 128;
          float a = at[r];
          if (u <= 0) tl0[hh] += a;
          else if (u >= 256) tl1[hh] += a;
          else skew[row*264 + u] = f2bf(a);
        }
        bfx4 pk;
#pragma unroll
        for (int r=0; r<4; ++r) pk[r] = (short)f2bf(at[r]);
        o[hh][0] = mfma16(lo4(vc8[hh][0]), pk, o[hh][0]);
        o[hh][1] = mfma16(hi4(vc8[hh][0]), pk, o[hh][1]);
        o[hh][2] = mfma16(lo4(vc8[hh][1]), pk, o[hh][2]);
        o[hh][3] = mfma16(hi4(vc8[hh][1]), pk, o[hh][3]);
      }
    } else {
      const bool hiSide = (ti < st);     // u >= 256 side
#pragma unroll
      for (int hh=0; hh<2; ++hh){
        f4 sc = mfma32(kc[hh][1], qf[hh][1], mfma32(kc[hh][0], qf[hh][0], fz));
        const float qa = hiSide ? qr1[hh] : qr0[hh];
        f4 at;
#pragma unroll
        for (int r=0; r<4; ++r) at[r] = __expf(sc[r] + qa) * is[r];
        float tsum = at[0] + at[1] + at[2] + at[3];
        if (hiSide) tl1[hh] += tsum; else tl0[hh] += tsum;
        bfx4 pk;
#pragma unroll
        for (int r=0; r<4; ++r) pk[r] = (short)f2bf(at[r]);
        o[hh][0] = mfma16(lo4(vc8[hh][0]), pk, o[hh][0]);
        o[hh][1] = mfma16(hi4(vc8[hh][0]), pk, o[hh][1]);
        o[hh][2] = mfma16(lo4(vc8[hh][1]), pk, o[hh][2]);
        o[hh][3] = mfma16(hi4(vc8[hh][1]), pk, o[hh][3]);
      }
    }

    if (ti < 63){
#pragma unroll
      for (int hh=0; hh<2; ++hh){
#pragma unroll
        for (int kf=0; kf<2; ++kf){ kc[hh][kf] = kn[hh][kf]; vc8[hh][kf] = vn8[hh][kf]; }
#pragma unroll
        for (int r=0; r<4; ++r) qc[hh][r] = qn[hh][r];
      }
      is = isn;
    }
  }

  __syncthreads();

  // ---- fused out2 = rel_v^T @ skew (own-wave rows only; local head rows) ----
  f4 acc2[2][4];
#pragma unroll
  for (int hh=0; hh<2; ++hh)
#pragma unroll
    for (int df=0; df<4; ++df) acc2[hh][df] = fz;
#pragma unroll
  for (int k0=0; k0<256; k0+=32){
    bfx8 bb0 = *(const bfx8*)&skew[(hl0*16 + p)*264 + k0 + 8*g];
    bfx8 bb1 = *(const bfx8*)&skew[((hl0+1)*16 + p)*264 + k0 + 8*g];
#pragma unroll
    for (int df=0; df<4; ++df){
      bfx8 a = *(const bfx8*)(relvT + (size_t)(df*16 + p)*288 + k0 + 8*g);
      acc2[0][df] = mfma32(a, bb0, acc2[0][df]);
      acc2[1][df] = mfma32(a, bb1, acc2[1][df]);
    }
  }

  f4 rv0[4], rv1[4];
#pragma unroll
  for (int df=0; df<4; ++df){
    rv0[df] = *(const f4*)(relv + df*16 + 4*g);
    rv1[df] = *(const f4*)(relv + 16384 + df*16 + 4*g);
  }
#pragma unroll
  for (int hh=0; hh<2; ++hh){
    float tv0 = tl0[hh];
    tv0 += __shfl_xor(tv0, 16, 64);
    tv0 += __shfl_xor(tv0, 32, 64);
    float tv1 = tl1[hh];
    tv1 += __shfl_xor(tv1, 16, 64);
    tv1 += __shfl_xor(tv1, 32, 64);
#pragma unroll
    for (int df=0; df<4; ++df)
#pragma unroll
      for (int r=0; r<4; ++r)
        o[hh][df][r] += acc2[hh][df][r] + tv0*rv0[df][r] + tv1*rv1[df][r];
  }

  __syncthreads();

  float* slabBase = (float*)skew;
  float (*tb)[68] = (float(*)[68])(slabBase + w*(16*68));
#pragma unroll
  for (int hh=0; hh<2; ++hh){
#pragma unroll
    for (int df=0; df<4; ++df)
      *(f4*)&tb[p][df*16 + 4*g] = o[hh][df];
    __syncthreads();
    const int srow = lane >> 2, quad = lane & 3;
    f4 r0 = *(const f4*)&tb[srow][quad*16 + 0];
    f4 r1 = *(const f4*)&tb[srow][quad*16 + 4];
    f4 r2 = *(const f4*)&tb[srow][quad*16 + 8];
    f4 r3 = *(const f4*)&tb[srow][quad*16 + 12];
    size_t addr = ((size_t)b*1024 + s0 + srow)*1024 + (h0+hh)*64 + quad*16;
    bfx8 pa, pb;
#pragma unroll
    for (int j=0; j<4; ++j){
      pa[j]   = (short)f2bf(r0[j]);
      pa[j+4] = (short)f2bf(r1[j]);
      pb[j]   = (short)f2bf(r2[j]);
      pb[j+4] = (short)f2bf(r3[j]);
    }
    *(bfx8*)(out1 + addr) = pa;
    *(bfx8*)(out1 + addr + 8) = pb;
    __syncthreads();
  }
}

// ---------------- final projection: counted-vmcnt double-buffered pipeline ----------------
__global__ __launch_bounds__(256) void k_wo(
    const unsigned short* __restrict__ out1, const unsigned short* __restrict__ wo,
    const float* __restrict__ bo, float* __restrict__ dout)
{
  __shared__ __align__(16) unsigned short smem[2][6144];
  const int nt = blockIdx.x;
  const int mt = blockIdx.y;
  const int w = threadIdx.x >> 6, lane = threadIdx.x & 63;
  const int wr = w >> 1, wc = w & 1;
  const int p = lane & 15, g = lane >> 4;
  const int m0 = mt*64, n0 = nt*128;
  const f4 fz = {0.f,0.f,0.f,0.f};
  f4 acc[2][4];
#pragma unroll
  for (int m=0;m<2;++m)
#pragma unroll
    for (int n=0;n<4;++n) acc[m][n] = fz;

  const int j0 = w*2, j1 = w*2 + 1;
  const unsigned short* gA = out1 + (size_t)(m0 + p)*1024 + g*8;
  const unsigned short* gB = wo   + (size_t)(n0 + p)*1024 + g*8;

  {
    unsigned short* d0 = &smem[0][0];
    gload16(gA + (size_t)w*16384, d0 + w*512);
    gload16(gB + (size_t)j0*16384, d0 + 2048 + j0*512);
    gload16(gB + (size_t)j1*16384, d0 + 2048 + j1*512);
  }

  for (int it=0; it<32; ++it){
    const int cur = it & 1;
    if (it < 31){
      const int kn = (it+1)*32;
      unsigned short* dn = &smem[cur^1][0];
      gload16(gA + (size_t)w*16384 + kn, dn + w*512);
      gload16(gB + (size_t)j0*16384 + kn, dn + 2048 + j0*512);
      gload16(gB + (size_t)j1*16384 + kn, dn + 2048 + j1*512);
      asm volatile("s_waitcnt vmcnt(3)" ::: "memory");
    } else {
      asm volatile("s_waitcnt vmcnt(0)" ::: "memory");
    }
    __builtin_amdgcn_sched_barrier(0);
    __builtin_amdgcn_s_barrier();
    __builtin_amdgcn_sched_barrier(0);
    {
      const unsigned short* Ab = &smem[cur][0];
      bfx8 af[2], bfr[4];
#pragma unroll
      for (int m=0;m<2;++m) af[m] = *(const bfx8*)(Ab + (wr*2+m)*512 + lane*8);
#pragma unroll
      for (int n=0;n<4;++n) bfr[n] = *(const bfx8*)(Ab + 2048 + (wc*4+n)*512 + lane*8);
#pragma unroll
      for (int m=0;m<2;++m)
#pragma unroll
        for (int n=0;n<4;++n)
          acc[m][n] = mfma32(af[m], bfr[n], acc[m][n]);
    }
    __builtin_amdgcn_sched_barrier(0);
    __builtin_amdgcn_s_barrier();
    __builtin_amdgcn_sched_barrier(0);
  }

#pragma unroll
  for (int n=0;n<4;++n){
    const int col = n0 + wc*64 + n*16 + p;
    const float bias = bo[col];
#pragma unroll
    for (int m=0;m<2;++m)
#pragma unroll
      for (int r=0;r<4;++r){
        int row = m0 + wr*32 + m*16 + 4*g + r;
        int bb = row >> 10, s = row & 1023;
        dout[((size_t)s*4 + bb)*1024 + col] = acc[m][n][r] + bias;
      }
  }
}

extern "C" void kernel_launch(void* const* d_in, const int* in_sizes, int n_in,
                              void* d_out, int out_size, void* d_ws, size_t ws_size,
                              hipStream_t stream){
  const float* x   = (const float*)d_in[0];
  const float* wq  = (const float*)d_in[1];
  const float* wk  = (const float*)d_in[2];
  const float* wv  = (const float*)d_in[3];
  const float* wo  = (const float*)d_in[4];
  const float* bo  = (const float*)d_in[5];
  const float* rlk = (const float*)d_in[6];
  const float* rlv = (const float*)d_in[7];
  char* ws = (char*)d_ws;

  unsigned short* x_bf    = (unsigned short*)(ws + 0);
  unsigned short* wq_bf   = (unsigned short*)(ws + 8388608);   // [wq|wk|wv|wo] contiguous
  unsigned short* relk_bf = (unsigned short*)(ws + 16777216);
  unsigned short* relvT_bf= (unsigned short*)(ws + 16812032);
  unsigned short* Qf      = (unsigned short*)(ws + 16848896);   // fragment layout
  unsigned short* Kf      = (unsigned short*)(ws + 25237504);   // fragment layout
  unsigned short* Vf      = (unsigned short*)(ws + 33626112);   // fragment layout
  unsigned short* Qr2     = (unsigned short*)(ws + 42014720);   // 35.65 MB -> 77666304
  unsigned short* out1    = (unsigned short*)(ws + 113317888);  // 8 MB
  float*          ivf     = (float*)        (ws + 121706496);  // 16 MB -> 138483712
  unsigned short* wo_bf   = (unsigned short*)(ws + 14680064);

  k_cast<<<4096, 256, 0, stream>>>(x, x_bf, 1048576);
  k_castw<<<dim3(1024,4), 256, 0, stream>>>(wq, wk, wv, wo, wq_bf);
  k_relprep<<<72, 256, 0, stream>>>(rlk, rlv, relk_bf, relvT_bf);

  k_qkv<<<dim3(24,4,8), 256, 0, stream>>>(x_bf, wq_bf, Qf, Kf, Vf);
  k_qr<<<512, 256, 0, stream>>>(Qf, relk_bf, Qr2);

  k_s   <<<2048, 512, 0, stream>>>(Qf, Kf, Qr2, ivf);
  k_attn<<<512, 256, 0, stream>>>(Qf, Kf, Vf, Qr2, ivf, relvT_bf, rlv, out1);
  k_wo<<<dim3(8,64), 256, 0, stream>>>(out1, wo_bf, bo, (float*)d_out);
}